// Round 1
// baseline (3855.504 us; speedup 1.0000x reference)
//
#include <hip/hip_runtime.h>
#include <hip/hip_bf16.h>
#include <cmath>

#define Bsz 2
#define Tt 1024
#define Cc 1024
#define Hh 16
#define NOPEd 32
#define ROPEDd 64
#define VDd 32
#define QLORAd 96
#define KVLORAd 32
#define BLKd 16
#define WINd 256
#define KEEPd 256
#define NBd 64
#define QDd 96
#define EPSF 1e-6f

static __device__ __forceinline__ float gelu_exact(float v) {
    return 0.5f * v * (1.f + erff(v * 0.70710678118654752f));
}

// blocksA[b*64+nb][blk*1024+c] = x[b][nb*16+blk][c] + pos_enc[blk][c]
__global__ void addpos_kernel(const float* __restrict__ x, const float* __restrict__ pos,
                              float* __restrict__ out) {
    int e = blockIdx.x * 256 + threadIdx.x;     // 128*16384 total
    int row = e >> 14;
    int k = e & 16383;
    int b = row >> 6, nb = row & 63;
    int blk = k >> 10, c = k & 1023;
    int t = nb * BLKd + blk;
    out[e] = x[(((long)b * Tt + t) << 10) + c] + pos[(blk << 10) + c];
}

// Generic tiled SGEMM: C[M,N] = A[M,K] @ B[K,N].
// M%64==0, N%64==0, K%(16*gridDim.z)==0. flags: bit1 = atomicAdd epilogue (split-K).
// a_rows: optional row indirection for A (gathered GEMM).
__global__ __launch_bounds__(256) void gemm_kernel(
    const float* __restrict__ A, const float* __restrict__ B, float* __restrict__ C,
    int M, int N, int K, const int* __restrict__ a_rows, int flags)
{
    __shared__ float As[16][65];   // transposed A tile, padded
    __shared__ float Bs[16][64];
    const int tid = threadIdx.x;
    const int bn = blockIdx.x * 64;
    const int bm = blockIdx.y * 64;
    const int kslice = K / gridDim.z;
    const int k_begin = blockIdx.z * kslice;
    const int k_end = k_begin + kslice;
    const int tx = tid & 15, ty = tid >> 4;
    float acc[4][4];
#pragma unroll
    for (int i = 0; i < 4; i++)
#pragma unroll
        for (int j = 0; j < 4; j++) acc[i][j] = 0.f;

    for (int k0 = k_begin; k0 < k_end; k0 += 16) {
#pragma unroll
        for (int l = 0; l < 4; l++) {
            int e = tid + l * 256;
            int r = e >> 4, kk = e & 15;
            int row = bm + r;
            int arow = a_rows ? a_rows[row] : row;
            As[kk][r] = A[(long)arow * K + k0 + kk];
        }
#pragma unroll
        for (int l = 0; l < 4; l++) {
            int e = tid + l * 256;
            int kk = e >> 6, c = e & 63;
            Bs[kk][c] = B[(long)(k0 + kk) * N + bn + c];
        }
        __syncthreads();
#pragma unroll
        for (int kk = 0; kk < 16; kk++) {
            float av[4], bv[4];
#pragma unroll
            for (int i = 0; i < 4; i++) av[i] = As[kk][ty * 4 + i];
#pragma unroll
            for (int j = 0; j < 4; j++) bv[j] = Bs[kk][tx * 4 + j];
#pragma unroll
            for (int i = 0; i < 4; i++)
#pragma unroll
                for (int j = 0; j < 4; j++) acc[i][j] += av[i] * bv[j];
        }
        __syncthreads();
    }
#pragma unroll
    for (int i = 0; i < 4; i++) {
        int row = bm + ty * 4 + i;
#pragma unroll
        for (int j = 0; j < 4; j++) {
            int col = bn + tx * 4 + j;
            long idx = (long)row * N + col;
            if (flags & 2) atomicAdd(&C[idx], acc[i][j]);
            else C[idx] = acc[i][j];
        }
    }
}

__global__ void gelu_kernel(float* __restrict__ h) {
    int e = blockIdx.x * 256 + threadIdx.x;
    h[e] = gelu_exact(h[e]);
}

// nq = RMSNorm(x @ Wcq) * qnw   [B*T, 96]
__global__ __launch_bounds__(256) void nq_kernel(const float* __restrict__ x,
    const float* __restrict__ Wcq, const float* __restrict__ qnw, float* __restrict__ nq)
{
    int tok = blockIdx.x, tid = threadIdx.x;
    __shared__ float xs[1024];
    __shared__ float part[192];
    __shared__ float vals[96];
    __shared__ float red[256];
    for (int c = tid; c < 1024; c += 256) xs[c] = x[((long)tok << 10) + c];
    __syncthreads();
    if (tid < 192) {
        int j = tid % 96, half = tid / 96;
        float acc = 0.f;
        int c0 = half * 512;
        for (int c = c0; c < c0 + 512; c++) acc += xs[c] * Wcq[c * 96 + j];
        part[tid] = acc;
    }
    __syncthreads();
    float sq = 0.f;
    if (tid < 96) { float v = part[tid] + part[tid + 96]; vals[tid] = v; sq = v * v; }
    red[tid] = sq; __syncthreads();
    for (int off = 128; off > 0; off >>= 1) { if (tid < off) red[tid] += red[tid + off]; __syncthreads(); }
    float mean = red[0] * (1.f / 96.f);
    if (tid < 96) nq[tok * 96 + tid] = vals[tid] * rsqrtf(mean + EPSF) * qnw[tid];
}

// q[tok][h*96+d]: d<32 -> nq@Wdqn head slice; d>=32 -> rope(nq@Wdqr) at position t
__global__ __launch_bounds__(256) void q_kernel(const float* __restrict__ nq,
    const float* __restrict__ Wdqn, const float* __restrict__ Wdqr, float* __restrict__ q)
{
    int tok = blockIdx.x, tid = threadIdx.x;
    int t = tok & (Tt - 1);
    __shared__ float ns[96];
    __shared__ float qn[512];
    __shared__ float qr[1024];
    if (tid < 96) ns[tid] = nq[tok * 96 + tid];
    __syncthreads();
#pragma unroll
    for (int l = 0; l < 2; l++) {
        int o = tid + l * 256;
        float acc = 0.f;
        for (int k = 0; k < 96; k++) acc += ns[k] * Wdqn[k * 512 + o];
        qn[o] = acc;
    }
#pragma unroll
    for (int l = 0; l < 4; l++) {
        int o = tid + l * 256;
        float acc = 0.f;
        for (int k = 0; k < 96; k++) acc += ns[k] * Wdqr[k * 1024 + o];
        qr[o] = acc;
    }
    __syncthreads();
#pragma unroll
    for (int l = 0; l < 6; l++) {
        int e = tid + l * 256;
        int h = e / 96, d = e % 96;
        float val;
        if (d < 32) val = qn[h * 32 + d];
        else {
            int dd = d - 32;
            int i = (dd < 32) ? dd : dd - 32;
            float freq = powf(10000.f, -(float)i / 32.f);
            float ang = (float)t * freq;
            float sn = sinf(ang), cs = cosf(ang);
            if (dd < 32) val = qr[h * 64 + dd] * cs - qr[h * 64 + dd + 32] * sn;
            else         val = qr[h * 64 + i] * sn + qr[h * 64 + dd] * cs;
        }
        q[(long)tok * 1536 + e] = val;
    }
}

// nkv = RMSNorm(cb @ Wckv) * kvnw   [128, 32]
__global__ __launch_bounds__(256) void nkv_kernel(const float* __restrict__ cb,
    const float* __restrict__ Wckv, const float* __restrict__ kvnw, float* __restrict__ nkv)
{
    int row = blockIdx.x, tid = threadIdx.x;
    __shared__ float cs[1024];
    __shared__ float red[256];
    __shared__ float vals[32];
    for (int c = tid; c < 1024; c += 256) cs[c] = cb[((long)row << 10) + c];
    __syncthreads();
    int j = tid & 31, g = tid >> 5;
    float acc = 0.f;
    for (int c = g * 128; c < g * 128 + 128; c++) acc += cs[c] * Wckv[c * 32 + j];
    red[tid] = acc; __syncthreads();
    if (tid < 128) red[tid] += red[tid + 128]; __syncthreads();
    if (tid < 64) red[tid] += red[tid + 64]; __syncthreads();
    if (tid < 32) { float v = red[tid] + red[tid + 32]; vals[tid] = v; red[tid] = v * v; }
    __syncthreads();
    if (tid < 16) red[tid] += red[tid + 16]; __syncthreads();
    if (tid < 8) red[tid] += red[tid + 8]; __syncthreads();
    if (tid < 4) red[tid] += red[tid + 4]; __syncthreads();
    if (tid < 2) red[tid] += red[tid + 2]; __syncthreads();
    if (tid < 1) red[0] += red[1]; __syncthreads();
    float mean = red[0] * (1.f / 32.f);
    if (tid < 32) nkv[row * 32 + tid] = vals[tid] * rsqrtf(mean + EPSF) * kvnw[tid];
}

// krope = rope((cb @ Wkr)/16) at position nb   [128, 64]
__global__ __launch_bounds__(256) void krope_kernel(const float* __restrict__ cb,
    const float* __restrict__ Wkr, float* __restrict__ krope)
{
    int row = blockIdx.x, tid = threadIdx.x;
    int nb = row & 63;
    __shared__ float cs[1024];
    __shared__ float red[256];
    __shared__ float raw[64];
    for (int c = tid; c < 1024; c += 256) cs[c] = cb[((long)row << 10) + c];
    __syncthreads();
    int d = tid & 63, g = tid >> 6;
    float acc = 0.f;
    for (int c = g * 256; c < g * 256 + 256; c++) acc += cs[c] * Wkr[c * 64 + d];
    red[tid] = acc; __syncthreads();
    if (tid < 128) red[tid] += red[tid + 128]; __syncthreads();
    if (tid < 64) raw[tid] = red[tid] + red[tid + 64];
    __syncthreads();
    if (tid < 64) {
        int dd = tid;
        int i = (dd < 32) ? dd : dd - 32;
        float freq = powf(10000.f, -(float)i / 32.f);
        float ang = (float)nb * freq;
        float sn = sinf(ang), c2 = cosf(ang);
        float val;
        if (dd < 32) val = raw[dd] * c2 - raw[dd + 32] * sn;
        else         val = raw[i] * sn + raw[dd] * c2;
        krope[row * 64 + dd] = val * (1.f / 16.f);
    }
}

// k1[row][h*96+d] = d<32 ? kn[row][h*32+d] : krope[row][d-32]
__global__ void k1_kernel(const float* __restrict__ kn, const float* __restrict__ krope,
                          float* __restrict__ k1) {
    int row = blockIdx.x, tid = threadIdx.x;
#pragma unroll
    for (int l = 0; l < 6; l++) {
        int e = tid + l * 256;
        int h = e / 96, d = e % 96;
        k1[(long)row * 1536 + e] = (d < 32) ? kn[row * 512 + h * 32 + d] : krope[row * 64 + d - 32];
    }
}

// imp[b*T+t] = x[b,t,:] . Wimp   (one wave per token)
__global__ void imp_kernel(const float* __restrict__ x, const float* __restrict__ Wimp,
                           float* __restrict__ imp) {
    int tid = threadIdx.x;
    int w = tid >> 6, lane = tid & 63;
    int tok = blockIdx.x * 4 + w;
    float acc = 0.f;
    for (int c = lane; c < 1024; c += 64) acc += x[((long)tok << 10) + c] * Wimp[c];
    for (int off = 32; off > 0; off >>= 1) acc += __shfl_down(acc, off);
    if (lane == 0) imp[tok] = acc;
}

// exact top-256 by rank (ties: lower index first, matching lax.top_k), sorted compaction
__global__ __launch_bounds__(256) void topk_kernel(const float* __restrict__ imp,
                                                   int* __restrict__ rows) {
    int b = blockIdx.x, tid = threadIdx.x;
    __shared__ float v[1024];
    __shared__ int flag[1024];
    for (int i = tid; i < 1024; i += 256) v[i] = imp[b * 1024 + i];
    __syncthreads();
    for (int i = tid; i < 1024; i += 256) {
        float vi = v[i]; int r = 0;
        for (int j = 0; j < 1024; j++) {
            float vj = v[j];
            r += (vj > vi) || (vj == vi && j < i);
        }
        flag[i] = (r < KEEPd) ? 1 : 0;
    }
    __syncthreads();
    for (int i = tid; i < 1024; i += 256) {
        if (flag[i]) {
            int p = 0;
            for (int j = 0; j < i; j++) p += flag[j];
            rows[b * KEEPd + p] = b * 1024 + i;
        }
    }
}

// One query per block; K/V staged through LDS; block softmax; unnormalized PV / sum.
// Kb: [B, SK, 1536] head stride 96; Vb: [B, SK, 512] head stride 32. windowed: causal 256-window.
__global__ __launch_bounds__(256) void attn_kernel(
    const float* __restrict__ q, const float* __restrict__ Kb, const float* __restrict__ Vb,
    float* __restrict__ o, int SK, int windowed)
{
    int t = blockIdx.x, h = blockIdx.y, b = blockIdx.z;
    int tid = threadIdx.x;
    int lo = 0, count = SK;
    if (windowed) { lo = t - (WINd - 1); if (lo < 0) lo = 0; count = t - lo + 1; }

    __shared__ float qs[96];
    __shared__ float p_lds[256];
    __shared__ float red[256];
    __shared__ float buf[256 * 33];   // Ks[256][17] then Vs[256][33]

    if (tid < 96) qs[tid] = q[((long)(b * Tt + t)) * 1536 + h * 96 + tid];

    const float* Kbase = Kb + ((long)b * SK) * 1536 + h * 96;
    float s = 0.f;
    for (int d0 = 0; d0 < 96; d0 += 16) {
        __syncthreads();
        for (int e = tid; e < count * 16; e += 256) {
            int key = e >> 4, dd = e & 15;
            buf[key * 17 + dd] = Kbase[(long)(lo + key) * 1536 + d0 + dd];
        }
        __syncthreads();
        if (tid < count) {
#pragma unroll
            for (int dd = 0; dd < 16; dd++) s += qs[d0 + dd] * buf[tid * 17 + dd];
        }
    }
    const float SCALEf = 0.10206207261596577f;
    s = (tid < count) ? s * SCALEf : -1e30f;

    __syncthreads();
    red[tid] = s; __syncthreads();
    for (int off = 128; off > 0; off >>= 1) { if (tid < off) red[tid] = fmaxf(red[tid], red[tid + off]); __syncthreads(); }
    float m = red[0];
    __syncthreads();
    float p = expf(s - m);
    p_lds[tid] = p;
    red[tid] = p; __syncthreads();
    for (int off = 128; off > 0; off >>= 1) { if (tid < off) red[tid] += red[tid + off]; __syncthreads(); }
    float sum = red[0];

    // PV
    const float* Vbase = Vb + ((long)b * SK) * 512 + h * 32;
    for (int e = tid; e < count * 32; e += 256) {
        int key = e >> 5, d = e & 31;
        buf[key * 33 + d] = Vbase[(long)(lo + key) * 512 + d];
    }
    __syncthreads();
    int d = tid & 31, g = tid >> 5;
    float acc = 0.f;
    for (int i = 0; i < 32; i++) {
        int key = g * 32 + i;
        if (key < count) acc += p_lds[key] * buf[key * 33 + d];
    }
    __syncthreads();
    red[tid] = acc; __syncthreads();
    if (tid < 128) red[tid] += red[tid + 128]; __syncthreads();
    if (tid < 64) red[tid] += red[tid + 64]; __syncthreads();
    if (tid < 32) {
        float r = red[tid] + red[tid + 32];
        o[((long)(b * Tt + t)) * 512 + h * 32 + tid] = r / sum;
    }
}

// gate softmax + weighted combine of the three branch outputs
__global__ __launch_bounds__(256) void gatecomb_kernel(const float* __restrict__ x,
    const float* __restrict__ Wgate, const float* __restrict__ o1,
    const float* __restrict__ o2, const float* __restrict__ o3, float* __restrict__ comb)
{
    int tok = blockIdx.x, tid = threadIdx.x;
    __shared__ float r0[256], r1[256], r2[256];
    float l0 = 0.f, l1 = 0.f, l2 = 0.f;
    for (int c = tid; c < 1024; c += 256) {
        float xv = x[((long)tok << 10) + c];
        l0 += xv * Wgate[c * 3 + 0];
        l1 += xv * Wgate[c * 3 + 1];
        l2 += xv * Wgate[c * 3 + 2];
    }
    r0[tid] = l0; r1[tid] = l1; r2[tid] = l2; __syncthreads();
    for (int off = 128; off > 0; off >>= 1) {
        if (tid < off) { r0[tid] += r0[tid + off]; r1[tid] += r1[tid + off]; r2[tid] += r2[tid + off]; }
        __syncthreads();
    }
    float a = r0[0], bb = r1[0], cc = r2[0];
    float m = fmaxf(a, fmaxf(bb, cc));
    float e0 = expf(a - m), e1 = expf(bb - m), e2 = expf(cc - m);
    float sinv = 1.f / (e0 + e1 + e2);
    float g0 = e0 * sinv, g1 = e1 * sinv, g2 = e2 * sinv;
    for (int i = tid; i < 512; i += 256) {
        long idx = (long)tok * 512 + i;
        comb[idx] = g0 * o1[idx] + g1 * o2[idx] + g2 * o3[idx];
    }
}

extern "C" void kernel_launch(void* const* d_in, const int* in_sizes, int n_in,
                              void* d_out, int out_size, void* d_ws, size_t ws_size,
                              hipStream_t stream)
{
    const float* x     = (const float*)d_in[0];
    const float* Wcq   = (const float*)d_in[1];
    const float* qnw   = (const float*)d_in[2];
    const float* Wdqn  = (const float*)d_in[3];
    const float* Wdqr  = (const float*)d_in[4];
    const float* Wckv  = (const float*)d_in[5];
    const float* kvnw  = (const float*)d_in[6];
    const float* Wdkn  = (const float*)d_in[7];
    const float* Wdv   = (const float*)d_in[8];
    const float* Wkr   = (const float*)d_in[9];
    const float* Wimp  = (const float*)d_in[10];
    const float* Wselk = (const float*)d_in[11];
    const float* Wselv = (const float*)d_in[12];
    const float* Wwink = (const float*)d_in[13];
    const float* Wwinv = (const float*)d_in[14];
    const float* Wc1   = (const float*)d_in[15];
    const float* Wc2   = (const float*)d_in[16];
    const float* pos   = (const float*)d_in[17];
    const float* Wgate = (const float*)d_in[18];
    const float* Wproj = (const float*)d_in[19];
    float* out = (float*)d_out;

    float* ws = (float*)d_ws;
    size_t off = 0;
    auto alloc = [&](size_t n) { float* p = ws + off; off += n; return p; };
    float* q       = alloc(2048L * 1536);
    float* blocksA = alloc(128L * 16384);
    float* hb      = alloc(128L * 4096);
    float* cb      = alloc(128L * 1024);
    float* nq      = alloc(2048L * 96);
    float* nkv     = alloc(128L * 32);
    float* kn      = alloc(128L * 512);
    float* v1      = alloc(128L * 512);
    float* krope   = alloc(128L * 64);
    float* k1      = alloc(128L * 1536);
    float* imp     = alloc(2048);
    float* winK    = alloc(2048L * 1536);
    float* winV    = alloc(2048L * 512);
    float* selK    = alloc(512L * 1536);
    float* selV    = alloc(512L * 512);
    float* o1      = alloc(2048L * 512);
    float* o2      = alloc(2048L * 512);
    float* o3      = alloc(2048L * 512);
    float* comb    = alloc(2048L * 512);
    int* rows      = (int*)alloc(512);

    // ---- branch 1: block compression ----
    hipMemsetAsync(hb, 0, 128L * 4096 * sizeof(float), stream);   // split-K accumulator
    addpos_kernel<<<8192, 256, 0, stream>>>(x, pos, blocksA);
    gemm_kernel<<<dim3(64, 2, 4), 256, 0, stream>>>(blocksA, Wc1, hb, 128, 4096, 16384, nullptr, 2);
    gelu_kernel<<<2048, 256, 0, stream>>>(hb);
    gemm_kernel<<<dim3(16, 2, 1), 256, 0, stream>>>(hb, Wc2, cb, 128, 1024, 4096, nullptr, 0);

    // ---- queries ----
    nq_kernel<<<2048, 256, 0, stream>>>(x, Wcq, qnw, nq);
    q_kernel<<<2048, 256, 0, stream>>>(nq, Wdqn, Wdqr, q);

    // ---- branch 1 K/V ----
    nkv_kernel<<<128, 256, 0, stream>>>(cb, Wckv, kvnw, nkv);
    gemm_kernel<<<dim3(8, 2, 1), 256, 0, stream>>>(nkv, Wdkn, kn, 128, 512, 32, nullptr, 0);
    gemm_kernel<<<dim3(8, 2, 1), 256, 0, stream>>>(nkv, Wdv, v1, 128, 512, 32, nullptr, 0);
    krope_kernel<<<128, 256, 0, stream>>>(cb, Wkr, krope);
    k1_kernel<<<128, 256, 0, stream>>>(kn, krope, k1);

    // ---- branch 2: top-k selection ----
    imp_kernel<<<512, 256, 0, stream>>>(x, Wimp, imp);
    topk_kernel<<<2, 256, 0, stream>>>(imp, rows);
    gemm_kernel<<<dim3(24, 8, 1), 256, 0, stream>>>(x, Wselk, selK, 512, 1536, 1024, rows, 0);
    gemm_kernel<<<dim3(8, 8, 1), 256, 0, stream>>>(x, Wselv, selV, 512, 512, 1024, rows, 0);

    // ---- branch 3: sliding window K/V ----
    gemm_kernel<<<dim3(24, 32, 1), 256, 0, stream>>>(x, Wwink, winK, 2048, 1536, 1024, nullptr, 0);
    gemm_kernel<<<dim3(8, 32, 1), 256, 0, stream>>>(x, Wwinv, winV, 2048, 512, 1024, nullptr, 0);

    // ---- attention (three branches) ----
    attn_kernel<<<dim3(Tt, Hh, Bsz), 256, 0, stream>>>(q, k1, v1, o1, 64, 0);
    attn_kernel<<<dim3(Tt, Hh, Bsz), 256, 0, stream>>>(q, selK, selV, o2, 256, 0);
    attn_kernel<<<dim3(Tt, Hh, Bsz), 256, 0, stream>>>(q, winK, winV, o3, 1024, 1);

    // ---- gate + combine + output projection ----
    gatecomb_kernel<<<2048, 256, 0, stream>>>(x, Wgate, o1, o2, o3, comb);
    gemm_kernel<<<dim3(16, 32, 1), 256, 0, stream>>>(comb, Wproj, out, 2048, 1024, 512, nullptr, 0);
}

// Round 2
// 2943.551 us; speedup vs baseline: 1.3098x; 1.3098x over previous
//
#include <hip/hip_runtime.h>
#include <hip/hip_bf16.h>
#include <cmath>

#define Bsz 2
#define Tt 1024
#define Cc 1024
#define Hh 16
#define WINd 256
#define KEEPd 256
#define EPSF 1e-6f

typedef __attribute__((ext_vector_type(8))) short bf16x8;
typedef __attribute__((ext_vector_type(4))) float f32x4;
typedef __attribute__((ext_vector_type(4))) float float4_t;
typedef __attribute__((ext_vector_type(2))) unsigned int uint2_t;

static __device__ __forceinline__ float gelu_exact(float v) {
    return 0.5f * v * (1.f + erff(v * 0.70710678118654752f));
}

static __device__ __forceinline__ unsigned int pack2bf(float lo, float hi) {
    unsigned a = __float_as_uint(lo);
    unsigned b = __float_as_uint(hi);
    a = (a + 0x7FFFu + ((a >> 16) & 1u)) >> 16;
    b = (b + 0x7FFFu + ((b >> 16) & 1u)) >> 16;
    return (b << 16) | (a & 0xFFFFu);
}

// blocksA[b*64+nb][blk*1024+c] = x[b][nb*16+blk][c] + pos_enc[blk][c]
__global__ void addpos_kernel(const float* __restrict__ x, const float* __restrict__ pos,
                              float* __restrict__ out) {
    int e = blockIdx.x * 256 + threadIdx.x;     // 128*16384 total
    int row = e >> 14;
    int k = e & 16383;
    int b = row >> 6, nb = row & 63;
    int blk = k >> 10, c = k & 1023;
    int t = nb * 16 + blk;
    out[e] = x[(((long)b * Tt + t) << 10) + c] + pos[(blk << 10) + c];
}

// bf16-MFMA GEMM: C[M,N] = A[M,K] @ B[K,N], fp32 in/out.
// M%128==0; N arbitrary (guarded); K/gridDim.z % 32 == 0.
// a_rows: optional absolute-row gather for A. flags bit1: atomicAdd epilogue (split-K).
// Tile 128x128, BK=32, 4 waves (2x2), each wave 64x64 via 4x4 16x16x32 MFMAs.
__global__ __launch_bounds__(256) void gemm_mfma(
    const float* __restrict__ A, const float* __restrict__ B, float* __restrict__ C,
    int M, int N, int K, const int* __restrict__ a_rows, int flags)
{
    __shared__ unsigned short As[128 * 40];  // row stride 40 ushorts = 80B (16B-aligned rows)
    __shared__ unsigned short Bs[128 * 40];  // Bs[n][k] (transposed during staging)
    const int tid = threadIdx.x;
    const int bn = blockIdx.x * 128;
    const int bm = blockIdx.y * 128;
    const int kslice = K / gridDim.z;
    const int k_begin = blockIdx.z * kslice;
    const int k_end = k_begin + kslice;

    const int lane = tid & 63;
    const int w = tid >> 6;
    const int wr = w >> 1, wc = w & 1;
    const int lr = lane & 15, lk = lane >> 4;

    f32x4 acc[4][4];
#pragma unroll
    for (int i = 0; i < 4; i++)
#pragma unroll
        for (int j = 0; j < 4; j++) acc[i][j] = (f32x4){0.f, 0.f, 0.f, 0.f};

    for (int k0 = k_begin; k0 < k_end; k0 += 32) {
        // ---- stage A tile 128x32 (fp32 -> bf16), layout As[row][k] ----
#pragma unroll
        for (int l = 0; l < 4; l++) {
            int u = tid + l * 256;          // 0..1023 float4 units
            int row = u >> 3, qq = u & 7;
            int arow = a_rows ? a_rows[bm + row] : bm + row;
            const float4_t va = *(const float4_t*)(A + (long)arow * K + k0 + qq * 4);
            uint2_t p;
            p.x = pack2bf(va.x, va.y);
            p.y = pack2bf(va.z, va.w);
            *(uint2_t*)&As[row * 40 + qq * 4] = p;
        }
        // ---- stage B tile 32x128 transposed -> Bs[n][k] ----
#pragma unroll
        for (int l = 0; l < 8; l++) {
            int u = tid + l * 256;          // 0..2047 (n, kpair) units
            int kp = u >> 7, n = u & 127;
            int col = bn + n;
            float lo = 0.f, hi = 0.f;
            if (col < N) {
                lo = B[(long)(k0 + 2 * kp) * N + col];
                hi = B[(long)(k0 + 2 * kp + 1) * N + col];
            }
            *(unsigned int*)&Bs[n * 40 + kp * 2] = pack2bf(lo, hi);
        }
        __syncthreads();
        bf16x8 af[4], bfr[4];
#pragma unroll
        for (int i = 0; i < 4; i++)
            af[i] = *(bf16x8*)&As[(wr * 64 + i * 16 + lr) * 40 + lk * 8];
#pragma unroll
        for (int j = 0; j < 4; j++)
            bfr[j] = *(bf16x8*)&Bs[(wc * 64 + j * 16 + lr) * 40 + lk * 8];
#pragma unroll
        for (int i = 0; i < 4; i++)
#pragma unroll
            for (int j = 0; j < 4; j++)
                acc[i][j] = __builtin_amdgcn_mfma_f32_16x16x32_bf16(af[i], bfr[j], acc[i][j], 0, 0, 0);
        __syncthreads();
    }

    // epilogue: D col=lane&15, row=(lane>>4)*4+reg
#pragma unroll
    for (int i = 0; i < 4; i++) {
#pragma unroll
        for (int j = 0; j < 4; j++) {
            int col = bn + wc * 64 + j * 16 + lr;
            if (col < N) {
#pragma unroll
                for (int r = 0; r < 4; r++) {
                    int row = bm + wr * 64 + i * 16 + lk * 4 + r;
                    long idx = (long)row * N + col;
                    if (flags & 2) atomicAdd(&C[idx], acc[i][j][r]);
                    else C[idx] = acc[i][j][r];
                }
            }
        }
    }
}

__global__ void gelu_kernel(float* __restrict__ h) {
    int e = blockIdx.x * 256 + threadIdx.x;
    h[e] = gelu_exact(h[e]);
}

// RMSNorm over 96-dim rows: out = v * rsqrt(mean(v^2)+eps) * w
__global__ __launch_bounds__(128) void rms96_kernel(const float* __restrict__ raw,
    const float* __restrict__ wgt, float* __restrict__ out)
{
    int tok = blockIdx.x, tid = threadIdx.x;
    __shared__ float sq[128];
    __shared__ float msh;
    float v = 0.f;
    if (tid < 96) v = raw[tok * 96 + tid];
    sq[tid] = v * v;
    __syncthreads();
    if (tid < 32) {
        float s = sq[tid] + sq[tid + 32] + sq[tid + 64];
        for (int off = 16; off > 0; off >>= 1) s += __shfl_down(s, off);
        if (tid == 0) msh = s * (1.f / 96.f);
    }
    __syncthreads();
    if (tid < 96) out[tok * 96 + tid] = v * rsqrtf(msh + EPSF) * wgt[tid];
}

// q[tok][h*96+d]: d<32 -> qn head slice; d>=32 -> rope(qr) at position t
__global__ __launch_bounds__(256) void rope_q_kernel(const float* __restrict__ qn,
    const float* __restrict__ qr, float* __restrict__ q)
{
    int tok = blockIdx.x, tid = threadIdx.x;
    int t = tok & (Tt - 1);
#pragma unroll
    for (int l = 0; l < 6; l++) {
        int e = tid + l * 256;
        int h = e / 96, d = e % 96;
        float val;
        if (d < 32) val = qn[(long)tok * 512 + h * 32 + d];
        else {
            int dd = d - 32;
            int i = (dd < 32) ? dd : dd - 32;
            float freq = powf(10000.f, -(float)i * (1.f / 32.f));
            float ang = (float)t * freq;
            float sn = sinf(ang), cs = cosf(ang);
            if (dd < 32) val = qr[(long)tok * 1024 + h * 64 + dd] * cs - qr[(long)tok * 1024 + h * 64 + dd + 32] * sn;
            else         val = qr[(long)tok * 1024 + h * 64 + i] * sn + qr[(long)tok * 1024 + h * 64 + dd] * cs;
        }
        q[(long)tok * 1536 + e] = val;
    }
}

// nkv = RMSNorm(cb @ Wckv) * kvnw   [128, 32]
__global__ __launch_bounds__(256) void nkv_kernel(const float* __restrict__ cb,
    const float* __restrict__ Wckv, const float* __restrict__ kvnw, float* __restrict__ nkv)
{
    int row = blockIdx.x, tid = threadIdx.x;
    __shared__ float cs[1024];
    __shared__ float red[256];
    __shared__ float vals[32];
    for (int c = tid; c < 1024; c += 256) cs[c] = cb[((long)row << 10) + c];
    __syncthreads();
    int j = tid & 31, g = tid >> 5;
    float acc = 0.f;
    for (int c = g * 128; c < g * 128 + 128; c++) acc += cs[c] * Wckv[c * 32 + j];
    red[tid] = acc; __syncthreads();
    if (tid < 128) red[tid] += red[tid + 128]; __syncthreads();
    if (tid < 64) red[tid] += red[tid + 64]; __syncthreads();
    if (tid < 32) { float v = red[tid] + red[tid + 32]; vals[tid] = v; red[tid] = v * v; }
    __syncthreads();
    if (tid < 16) red[tid] += red[tid + 16]; __syncthreads();
    if (tid < 8) red[tid] += red[tid + 8]; __syncthreads();
    if (tid < 4) red[tid] += red[tid + 4]; __syncthreads();
    if (tid < 2) red[tid] += red[tid + 2]; __syncthreads();
    if (tid < 1) red[0] += red[1]; __syncthreads();
    float mean = red[0] * (1.f / 32.f);
    if (tid < 32) nkv[row * 32 + tid] = vals[tid] * rsqrtf(mean + EPSF) * kvnw[tid];
}

// krope = rope((cb @ Wkr)/16) at position nb   [128, 64]
__global__ __launch_bounds__(256) void krope_kernel(const float* __restrict__ cb,
    const float* __restrict__ Wkr, float* __restrict__ krope)
{
    int row = blockIdx.x, tid = threadIdx.x;
    int nb = row & 63;
    __shared__ float cs[1024];
    __shared__ float red[256];
    __shared__ float raw[64];
    for (int c = tid; c < 1024; c += 256) cs[c] = cb[((long)row << 10) + c];
    __syncthreads();
    int d = tid & 63, g = tid >> 6;
    float acc = 0.f;
    for (int c = g * 256; c < g * 256 + 256; c++) acc += cs[c] * Wkr[c * 64 + d];
    red[tid] = acc; __syncthreads();
    if (tid < 128) red[tid] += red[tid + 128]; __syncthreads();
    if (tid < 64) raw[tid] = red[tid] + red[tid + 64];
    __syncthreads();
    if (tid < 64) {
        int dd = tid;
        int i = (dd < 32) ? dd : dd - 32;
        float freq = powf(10000.f, -(float)i * (1.f / 32.f));
        float ang = (float)nb * freq;
        float sn = sinf(ang), c2 = cosf(ang);
        float val;
        if (dd < 32) val = raw[dd] * c2 - raw[dd + 32] * sn;
        else         val = raw[i] * sn + raw[dd] * c2;
        krope[row * 64 + dd] = val * (1.f / 16.f);
    }
}

// k1[row][h*96+d] = d<32 ? kn[row][h*32+d] : krope[row][d-32]
__global__ void k1_kernel(const float* __restrict__ kn, const float* __restrict__ krope,
                          float* __restrict__ k1) {
    int row = blockIdx.x, tid = threadIdx.x;
#pragma unroll
    for (int l = 0; l < 6; l++) {
        int e = tid + l * 256;
        int h = e / 96, d = e % 96;
        k1[(long)row * 1536 + e] = (d < 32) ? kn[row * 512 + h * 32 + d] : krope[row * 64 + d - 32];
    }
}

// imp[b*T+t] = x[b,t,:] . Wimp   (fp32: feeds discrete top-k)
__global__ void imp_kernel(const float* __restrict__ x, const float* __restrict__ Wimp,
                           float* __restrict__ imp) {
    int tid = threadIdx.x;
    int w = tid >> 6, lane = tid & 63;
    int tok = blockIdx.x * 4 + w;
    float acc = 0.f;
    for (int c = lane; c < 1024; c += 64) acc += x[((long)tok << 10) + c] * Wimp[c];
    for (int off = 32; off > 0; off >>= 1) acc += __shfl_down(acc, off);
    if (lane == 0) imp[tok] = acc;
}

// exact top-256 by rank (ties: lower index first), sorted compaction
__global__ __launch_bounds__(256) void topk_kernel(const float* __restrict__ imp,
                                                   int* __restrict__ rows) {
    int b = blockIdx.x, tid = threadIdx.x;
    __shared__ float v[1024];
    __shared__ int flag[1024];
    for (int i = tid; i < 1024; i += 256) v[i] = imp[b * 1024 + i];
    __syncthreads();
    for (int i = tid; i < 1024; i += 256) {
        float vi = v[i]; int r = 0;
        for (int j = 0; j < 1024; j++) {
            float vj = v[j];
            r += (vj > vi) || (vj == vi && j < i);
        }
        flag[i] = (r < KEEPd) ? 1 : 0;
    }
    __syncthreads();
    for (int i = tid; i < 1024; i += 256) {
        if (flag[i]) {
            int p = 0;
            for (int j = 0; j < i; j++) p += flag[j];
            rows[b * KEEPd + p] = b * 1024 + i;
        }
    }
}

// One query per block; K/V staged through LDS; block softmax.
__global__ __launch_bounds__(256) void attn_kernel(
    const float* __restrict__ q, const float* __restrict__ Kb, const float* __restrict__ Vb,
    float* __restrict__ o, int SK, int windowed)
{
    int t = blockIdx.x, h = blockIdx.y, b = blockIdx.z;
    int tid = threadIdx.x;
    int lo = 0, count = SK;
    if (windowed) { lo = t - (WINd - 1); if (lo < 0) lo = 0; count = t - lo + 1; }

    __shared__ float qs[96];
    __shared__ float p_lds[256];
    __shared__ float red[256];
    __shared__ float buf[256 * 33];

    if (tid < 96) qs[tid] = q[((long)(b * Tt + t)) * 1536 + h * 96 + tid];

    const float* Kbase = Kb + ((long)b * SK) * 1536 + h * 96;
    float s = 0.f;
    for (int d0 = 0; d0 < 96; d0 += 16) {
        __syncthreads();
        for (int e = tid; e < count * 16; e += 256) {
            int key = e >> 4, dd = e & 15;
            buf[key * 17 + dd] = Kbase[(long)(lo + key) * 1536 + d0 + dd];
        }
        __syncthreads();
        if (tid < count) {
#pragma unroll
            for (int dd = 0; dd < 16; dd++) s += qs[d0 + dd] * buf[tid * 17 + dd];
        }
    }
    const float SCALEf = 0.10206207261596577f;
    s = (tid < count) ? s * SCALEf : -1e30f;

    __syncthreads();
    red[tid] = s; __syncthreads();
    for (int off = 128; off > 0; off >>= 1) { if (tid < off) red[tid] = fmaxf(red[tid], red[tid + off]); __syncthreads(); }
    float m = red[0];
    __syncthreads();
    float p = expf(s - m);
    p_lds[tid] = p;
    red[tid] = p; __syncthreads();
    for (int off = 128; off > 0; off >>= 1) { if (tid < off) red[tid] += red[tid + off]; __syncthreads(); }
    float sum = red[0];

    const float* Vbase = Vb + ((long)b * SK) * 512 + h * 32;
    for (int e = tid; e < count * 32; e += 256) {
        int key = e >> 5, d = e & 31;
        buf[key * 33 + d] = Vbase[(long)(lo + key) * 512 + d];
    }
    __syncthreads();
    int d = tid & 31, g = tid >> 5;
    float acc = 0.f;
    for (int i = 0; i < 32; i++) {
        int key = g * 32 + i;
        if (key < count) acc += p_lds[key] * buf[key * 33 + d];
    }
    __syncthreads();
    red[tid] = acc; __syncthreads();
    if (tid < 128) red[tid] += red[tid + 128]; __syncthreads();
    if (tid < 64) red[tid] += red[tid + 64]; __syncthreads();
    if (tid < 32) {
        float r = red[tid] + red[tid + 32];
        o[((long)(b * Tt + t)) * 512 + h * 32 + tid] = r / sum;
    }
}

// gate softmax + weighted combine of the three branch outputs (fp32)
__global__ __launch_bounds__(256) void gatecomb_kernel(const float* __restrict__ x,
    const float* __restrict__ Wgate, const float* __restrict__ o1,
    const float* __restrict__ o2, const float* __restrict__ o3, float* __restrict__ comb)
{
    int tok = blockIdx.x, tid = threadIdx.x;
    __shared__ float r0[256], r1[256], r2[256];
    float l0 = 0.f, l1 = 0.f, l2 = 0.f;
    for (int c = tid; c < 1024; c += 256) {
        float xv = x[((long)tok << 10) + c];
        l0 += xv * Wgate[c * 3 + 0];
        l1 += xv * Wgate[c * 3 + 1];
        l2 += xv * Wgate[c * 3 + 2];
    }
    r0[tid] = l0; r1[tid] = l1; r2[tid] = l2; __syncthreads();
    for (int off = 128; off > 0; off >>= 1) {
        if (tid < off) { r0[tid] += r0[tid + off]; r1[tid] += r1[tid + off]; r2[tid] += r2[tid + off]; }
        __syncthreads();
    }
    float a = r0[0], bb = r1[0], cc = r2[0];
    float m = fmaxf(a, fmaxf(bb, cc));
    float e0 = expf(a - m), e1 = expf(bb - m), e2 = expf(cc - m);
    float sinv = 1.f / (e0 + e1 + e2);
    float g0 = e0 * sinv, g1 = e1 * sinv, g2 = e2 * sinv;
    for (int i = tid; i < 512; i += 256) {
        long idx = (long)tok * 512 + i;
        comb[idx] = g0 * o1[idx] + g1 * o2[idx] + g2 * o3[idx];
    }
}

extern "C" void kernel_launch(void* const* d_in, const int* in_sizes, int n_in,
                              void* d_out, int out_size, void* d_ws, size_t ws_size,
                              hipStream_t stream)
{
    const float* x     = (const float*)d_in[0];
    const float* Wcq   = (const float*)d_in[1];
    const float* qnw   = (const float*)d_in[2];
    const float* Wdqn  = (const float*)d_in[3];
    const float* Wdqr  = (const float*)d_in[4];
    const float* Wckv  = (const float*)d_in[5];
    const float* kvnw  = (const float*)d_in[6];
    const float* Wdkn  = (const float*)d_in[7];
    const float* Wdv   = (const float*)d_in[8];
    const float* Wkr   = (const float*)d_in[9];
    const float* Wimp  = (const float*)d_in[10];
    const float* Wselk = (const float*)d_in[11];
    const float* Wselv = (const float*)d_in[12];
    const float* Wwink = (const float*)d_in[13];
    const float* Wwinv = (const float*)d_in[14];
    const float* Wc1   = (const float*)d_in[15];
    const float* Wc2   = (const float*)d_in[16];
    const float* pos   = (const float*)d_in[17];
    const float* Wgate = (const float*)d_in[18];
    const float* Wproj = (const float*)d_in[19];
    float* out = (float*)d_out;

    float* ws = (float*)d_ws;
    size_t off = 0;
    auto alloc = [&](size_t n) { float* p = ws + off; off += n; return p; };
    float* q       = alloc(2048L * 1536);
    float* blocksA = alloc(128L * 16384);   // reused as qr after Wc1 GEMM
    float* hb      = alloc(128L * 4096);
    float* cb      = alloc(128L * 1024);
    float* nqraw   = alloc(2048L * 96);
    float* nq      = alloc(2048L * 96);
    float* qn      = alloc(2048L * 512);
    float* nkv     = alloc(128L * 32);
    float* kn      = alloc(128L * 512);
    float* v1      = alloc(128L * 512);
    float* krope   = alloc(128L * 64);
    float* k1      = alloc(128L * 1536);
    float* imp     = alloc(2048);
    float* winK    = alloc(2048L * 1536);
    float* winV    = alloc(2048L * 512);
    float* selK    = alloc(512L * 1536);
    float* selV    = alloc(512L * 512);
    float* o1      = alloc(2048L * 512);
    float* o2      = alloc(2048L * 512);
    float* o3      = alloc(2048L * 512);
    float* comb    = alloc(2048L * 512);
    int* rows      = (int*)alloc(512);
    float* qr      = blocksA;               // alias: qr computed after blocksA consumed

    // ---- branch 1: block compression ----
    addpos_kernel<<<8192, 256, 0, stream>>>(x, pos, blocksA);
    hipMemsetAsync(hb, 0, 128L * 4096 * sizeof(float), stream);
    gemm_mfma<<<dim3(32, 1, 8), 256, 0, stream>>>(blocksA, Wc1, hb, 128, 4096, 16384, nullptr, 2);
    gelu_kernel<<<2048, 256, 0, stream>>>(hb);
    hipMemsetAsync(cb, 0, 128L * 1024 * sizeof(float), stream);
    gemm_mfma<<<dim3(8, 1, 8), 256, 0, stream>>>(hb, Wc2, cb, 128, 1024, 4096, nullptr, 2);

    // ---- queries (GEMM path) ----
    hipMemsetAsync(nqraw, 0, 2048L * 96 * sizeof(float), stream);
    gemm_mfma<<<dim3(1, 16, 4), 256, 0, stream>>>(x, Wcq, nqraw, 2048, 96, 1024, nullptr, 2);
    rms96_kernel<<<2048, 128, 0, stream>>>(nqraw, qnw, nq);
    gemm_mfma<<<dim3(4, 16, 1), 256, 0, stream>>>(nq, Wdqn, qn, 2048, 512, 96, nullptr, 0);
    gemm_mfma<<<dim3(8, 16, 1), 256, 0, stream>>>(nq, Wdqr, qr, 2048, 1024, 96, nullptr, 0);
    rope_q_kernel<<<2048, 256, 0, stream>>>(qn, qr, q);

    // ---- branch 1 K/V ----
    nkv_kernel<<<128, 256, 0, stream>>>(cb, Wckv, kvnw, nkv);
    gemm_mfma<<<dim3(4, 1, 1), 256, 0, stream>>>(nkv, Wdkn, kn, 128, 512, 32, nullptr, 0);
    gemm_mfma<<<dim3(4, 1, 1), 256, 0, stream>>>(nkv, Wdv, v1, 128, 512, 32, nullptr, 0);
    krope_kernel<<<128, 256, 0, stream>>>(cb, Wkr, krope);
    k1_kernel<<<128, 256, 0, stream>>>(kn, krope, k1);

    // ---- branch 2: top-k selection ----
    imp_kernel<<<512, 256, 0, stream>>>(x, Wimp, imp);
    topk_kernel<<<2, 256, 0, stream>>>(imp, rows);
    hipMemsetAsync(selK, 0, 512L * 1536 * sizeof(float), stream);
    hipMemsetAsync(selV, 0, 512L * 512 * sizeof(float), stream);
    gemm_mfma<<<dim3(12, 4, 4), 256, 0, stream>>>(x, Wselk, selK, 512, 1536, 1024, rows, 2);
    gemm_mfma<<<dim3(4, 4, 8), 256, 0, stream>>>(x, Wselv, selV, 512, 512, 1024, rows, 2);

    // ---- branch 3: sliding window K/V ----
    gemm_mfma<<<dim3(12, 16, 1), 256, 0, stream>>>(x, Wwink, winK, 2048, 1536, 1024, nullptr, 0);
    hipMemsetAsync(winV, 0, 2048L * 512 * sizeof(float), stream);
    gemm_mfma<<<dim3(4, 16, 2), 256, 0, stream>>>(x, Wwinv, winV, 2048, 512, 1024, nullptr, 2);

    // ---- attention (three branches, fp32) ----
    attn_kernel<<<dim3(Tt, Hh, Bsz), 256, 0, stream>>>(q, k1, v1, o1, 64, 0);
    attn_kernel<<<dim3(Tt, Hh, Bsz), 256, 0, stream>>>(q, selK, selV, o2, 256, 0);
    attn_kernel<<<dim3(Tt, Hh, Bsz), 256, 0, stream>>>(q, winK, winV, o3, 1024, 1);

    // ---- gate + combine + output projection ----
    gatecomb_kernel<<<2048, 256, 0, stream>>>(x, Wgate, o1, o2, o3, comb);
    gemm_mfma<<<dim3(8, 16, 1), 256, 0, stream>>>(comb, Wproj, out, 2048, 1024, 512, nullptr, 0);
}

// Round 4
// 1682.949 us; speedup vs baseline: 2.2909x; 1.7490x over previous
//
#include <hip/hip_runtime.h>
#include <hip/hip_bf16.h>
#include <cmath>

#define Bsz 2
#define Tt 1024
#define Cc 1024
#define Hh 16
#define WINd 256
#define KEEPd 256
#define EPSF 1e-6f

typedef __attribute__((ext_vector_type(8))) short bf16x8;
typedef __attribute__((ext_vector_type(4))) float f32x4;
typedef __attribute__((ext_vector_type(4))) float float4_t;
typedef __attribute__((ext_vector_type(2))) unsigned int uint2_t;

static __device__ __forceinline__ float gelu_exact(float v) {
    return 0.5f * v * (1.f + erff(v * 0.70710678118654752f));
}

static __device__ __forceinline__ unsigned int pack2bf(float lo, float hi) {
    unsigned a = __float_as_uint(lo);
    unsigned b = __float_as_uint(hi);
    a = (a + 0x7FFFu + ((a >> 16) & 1u)) >> 16;
    b = (b + 0x7FFFu + ((b >> 16) & 1u)) >> 16;
    return (b << 16) | (a & 0xFFFFu);
}

static __device__ __forceinline__ unsigned short bf16of(float v) {
    unsigned a = __float_as_uint(v);
    a = (a + 0x7FFFu + ((a >> 16) & 1u)) >> 16;
    return (unsigned short)a;
}

// blocksA[b*64+nb][blk*1024+c] = x[b][nb*16+blk][c] + pos_enc[blk][c]
__global__ void addpos_kernel(const float* __restrict__ x, const float* __restrict__ pos,
                              float* __restrict__ out) {
    int e = blockIdx.x * 256 + threadIdx.x;     // 128*16384 total
    int row = e >> 14;
    int k = e & 16383;
    int b = row >> 6, nb = row & 63;
    int blk = k >> 10, c = k & 1023;
    int t = nb * 16 + blk;
    out[e] = x[(((long)b * Tt + t) << 10) + c] + pos[(blk << 10) + c];
}

// bf16-MFMA GEMM: C[M,N] = A[M,K] @ B[K,N], fp32 in/out.
__global__ __launch_bounds__(256) void gemm_mfma(
    const float* __restrict__ A, const float* __restrict__ B, float* __restrict__ C,
    int M, int N, int K, const int* __restrict__ a_rows, int flags)
{
    __shared__ unsigned short As[128 * 40];
    __shared__ unsigned short Bs[128 * 40];
    const int tid = threadIdx.x;
    const int bn = blockIdx.x * 128;
    const int bm = blockIdx.y * 128;
    const int kslice = K / gridDim.z;
    const int k_begin = blockIdx.z * kslice;
    const int k_end = k_begin + kslice;

    const int lane = tid & 63;
    const int w = tid >> 6;
    const int wr = w >> 1, wc = w & 1;
    const int lr = lane & 15, lk = lane >> 4;

    f32x4 acc[4][4];
#pragma unroll
    for (int i = 0; i < 4; i++)
#pragma unroll
        for (int j = 0; j < 4; j++) acc[i][j] = (f32x4){0.f, 0.f, 0.f, 0.f};

    for (int k0 = k_begin; k0 < k_end; k0 += 32) {
#pragma unroll
        for (int l = 0; l < 4; l++) {
            int u = tid + l * 256;
            int row = u >> 3, qq = u & 7;
            int arow = a_rows ? a_rows[bm + row] : bm + row;
            const float4_t va = *(const float4_t*)(A + (long)arow * K + k0 + qq * 4);
            uint2_t p;
            p.x = pack2bf(va.x, va.y);
            p.y = pack2bf(va.z, va.w);
            *(uint2_t*)&As[row * 40 + qq * 4] = p;
        }
#pragma unroll
        for (int l = 0; l < 8; l++) {
            int u = tid + l * 256;
            int kp = u >> 7, n = u & 127;
            int col = bn + n;
            float lo = 0.f, hi = 0.f;
            if (col < N) {
                lo = B[(long)(k0 + 2 * kp) * N + col];
                hi = B[(long)(k0 + 2 * kp + 1) * N + col];
            }
            *(unsigned int*)&Bs[n * 40 + kp * 2] = pack2bf(lo, hi);
        }
        __syncthreads();
        bf16x8 af[4], bfr[4];
#pragma unroll
        for (int i = 0; i < 4; i++)
            af[i] = *(bf16x8*)&As[(wr * 64 + i * 16 + lr) * 40 + lk * 8];
#pragma unroll
        for (int j = 0; j < 4; j++)
            bfr[j] = *(bf16x8*)&Bs[(wc * 64 + j * 16 + lr) * 40 + lk * 8];
#pragma unroll
        for (int i = 0; i < 4; i++)
#pragma unroll
            for (int j = 0; j < 4; j++)
                acc[i][j] = __builtin_amdgcn_mfma_f32_16x16x32_bf16(af[i], bfr[j], acc[i][j], 0, 0, 0);
        __syncthreads();
    }

#pragma unroll
    for (int i = 0; i < 4; i++) {
#pragma unroll
        for (int j = 0; j < 4; j++) {
            int col = bn + wc * 64 + j * 16 + lr;
            if (col < N) {
#pragma unroll
                for (int r = 0; r < 4; r++) {
                    int row = bm + wr * 64 + i * 16 + lk * 4 + r;
                    long idx = (long)row * N + col;
                    if (flags & 2) atomicAdd(&C[idx], acc[i][j][r]);
                    else C[idx] = acc[i][j][r];
                }
            }
        }
    }
}

__global__ void gelu_kernel(float* __restrict__ h) {
    int e = blockIdx.x * 256 + threadIdx.x;
    h[e] = gelu_exact(h[e]);
}

// RMSNorm over 96-dim rows
__global__ __launch_bounds__(128) void rms96_kernel(const float* __restrict__ raw,
    const float* __restrict__ wgt, float* __restrict__ out)
{
    int tok = blockIdx.x, tid = threadIdx.x;
    __shared__ float sq[128];
    __shared__ float msh;
    float v = 0.f;
    if (tid < 96) v = raw[tok * 96 + tid];
    sq[tid] = v * v;
    __syncthreads();
    if (tid < 32) {
        float s = sq[tid] + sq[tid + 32] + sq[tid + 64];
        for (int off = 16; off > 0; off >>= 1) s += __shfl_down(s, off);
        if (tid == 0) msh = s * (1.f / 96.f);
    }
    __syncthreads();
    if (tid < 96) out[tok * 96 + tid] = v * rsqrtf(msh + EPSF) * wgt[tid];
}

// q[tok][h*96+d]: d<32 -> qn head slice; d>=32 -> rope(qr) at position t
__global__ __launch_bounds__(256) void rope_q_kernel(const float* __restrict__ qn,
    const float* __restrict__ qr, float* __restrict__ q)
{
    int tok = blockIdx.x, tid = threadIdx.x;
    int t = tok & (Tt - 1);
#pragma unroll
    for (int l = 0; l < 6; l++) {
        int e = tid + l * 256;
        int h = e / 96, d = e % 96;
        float val;
        if (d < 32) val = qn[(long)tok * 512 + h * 32 + d];
        else {
            int dd = d - 32;
            int i = (dd < 32) ? dd : dd - 32;
            float freq = powf(10000.f, -(float)i * (1.f / 32.f));
            float ang = (float)t * freq;
            float sn = sinf(ang), cs = cosf(ang);
            if (dd < 32) val = qr[(long)tok * 1024 + h * 64 + dd] * cs - qr[(long)tok * 1024 + h * 64 + dd + 32] * sn;
            else         val = qr[(long)tok * 1024 + h * 64 + i] * sn + qr[(long)tok * 1024 + h * 64 + dd] * cs;
        }
        q[(long)tok * 1536 + e] = val;
    }
}

// nkv = RMSNorm(cb @ Wckv) * kvnw   [128, 32]
__global__ __launch_bounds__(256) void nkv_kernel(const float* __restrict__ cb,
    const float* __restrict__ Wckv, const float* __restrict__ kvnw, float* __restrict__ nkv)
{
    int row = blockIdx.x, tid = threadIdx.x;
    __shared__ float cs[1024];
    __shared__ float red[256];
    __shared__ float vals[32];
    for (int c = tid; c < 1024; c += 256) cs[c] = cb[((long)row << 10) + c];
    __syncthreads();
    int j = tid & 31, g = tid >> 5;
    float acc = 0.f;
    for (int c = g * 128; c < g * 128 + 128; c++) acc += cs[c] * Wckv[c * 32 + j];
    red[tid] = acc; __syncthreads();
    if (tid < 128) red[tid] += red[tid + 128]; __syncthreads();
    if (tid < 64) red[tid] += red[tid + 64]; __syncthreads();
    if (tid < 32) { float v = red[tid] + red[tid + 32]; vals[tid] = v; red[tid] = v * v; }
    __syncthreads();
    if (tid < 16) red[tid] += red[tid + 16]; __syncthreads();
    if (tid < 8) red[tid] += red[tid + 8]; __syncthreads();
    if (tid < 4) red[tid] += red[tid + 4]; __syncthreads();
    if (tid < 2) red[tid] += red[tid + 2]; __syncthreads();
    if (tid < 1) red[0] += red[1]; __syncthreads();
    float mean = red[0] * (1.f / 32.f);
    if (tid < 32) nkv[row * 32 + tid] = vals[tid] * rsqrtf(mean + EPSF) * kvnw[tid];
}

// krope = rope((cb @ Wkr)/16) at position nb   [128, 64]
__global__ __launch_bounds__(256) void krope_kernel(const float* __restrict__ cb,
    const float* __restrict__ Wkr, float* __restrict__ krope)
{
    int row = blockIdx.x, tid = threadIdx.x;
    int nb = row & 63;
    __shared__ float cs[1024];
    __shared__ float red[256];
    __shared__ float raw[64];
    for (int c = tid; c < 1024; c += 256) cs[c] = cb[((long)row << 10) + c];
    __syncthreads();
    int d = tid & 63, g = tid >> 6;
    float acc = 0.f;
    for (int c = g * 256; c < g * 256 + 256; c++) acc += cs[c] * Wkr[c * 64 + d];
    red[tid] = acc; __syncthreads();
    if (tid < 128) red[tid] += red[tid + 128]; __syncthreads();
    if (tid < 64) raw[tid] = red[tid] + red[tid + 64];
    __syncthreads();
    if (tid < 64) {
        int dd = tid;
        int i = (dd < 32) ? dd : dd - 32;
        float freq = powf(10000.f, -(float)i * (1.f / 32.f));
        float ang = (float)nb * freq;
        float sn = sinf(ang), c2 = cosf(ang);
        float val;
        if (dd < 32) val = raw[dd] * c2 - raw[dd + 32] * sn;
        else         val = raw[i] * sn + raw[dd] * c2;
        krope[row * 64 + dd] = val * (1.f / 16.f);
    }
}

// k1[row][h*96+d] = d<32 ? kn[row][h*32+d] : krope[row][d-32]
__global__ void k1_kernel(const float* __restrict__ kn, const float* __restrict__ krope,
                          float* __restrict__ k1) {
    int row = blockIdx.x, tid = threadIdx.x;
#pragma unroll
    for (int l = 0; l < 6; l++) {
        int e = tid + l * 256;
        int h = e / 96, d = e % 96;
        k1[(long)row * 1536 + e] = (d < 32) ? kn[row * 512 + h * 32 + d] : krope[row * 64 + d - 32];
    }
}

// imp[b*T+t] = x[b,t,:] . Wimp
__global__ void imp_kernel(const float* __restrict__ x, const float* __restrict__ Wimp,
                           float* __restrict__ imp) {
    int tid = threadIdx.x;
    int w = tid >> 6, lane = tid & 63;
    int tok = blockIdx.x * 4 + w;
    float acc = 0.f;
    for (int c = lane; c < 1024; c += 64) acc += x[((long)tok << 10) + c] * Wimp[c];
    for (int off = 32; off > 0; off >>= 1) acc += __shfl_down(acc, off);
    if (lane == 0) imp[tok] = acc;
}

// exact top-256 by rank, sorted compaction
__global__ __launch_bounds__(256) void topk_kernel(const float* __restrict__ imp,
                                                   int* __restrict__ rows) {
    int b = blockIdx.x, tid = threadIdx.x;
    __shared__ float v[1024];
    __shared__ int flag[1024];
    for (int i = tid; i < 1024; i += 256) v[i] = imp[b * 1024 + i];
    __syncthreads();
    for (int i = tid; i < 1024; i += 256) {
        float vi = v[i]; int r = 0;
        for (int j = 0; j < 1024; j++) {
            float vj = v[j];
            r += (vj > vi) || (vj == vi && j < i);
        }
        flag[i] = (r < KEEPd) ? 1 : 0;
    }
    __syncthreads();
    for (int i = tid; i < 1024; i += 256) {
        if (flag[i]) {
            int p = 0;
            for (int j = 0; j < i; j++) p += flag[j];
            rows[b * KEEPd + p] = b * 1024 + i;
        }
    }
}

// MFMA flash attention: one block = (b, h, 64-query tile); 4 waves x 16 queries.
// Kb: [B, SK, 1536] head stride 96; Vb: [B, SK, 512] head stride 32.
// windowed: causal 256-window (SK == Tt).
__global__ __launch_bounds__(256) void attn_mfma(
    const float* __restrict__ q, const float* __restrict__ Kb, const float* __restrict__ Vb,
    float* __restrict__ o, int SK, int windowed)
{
    const int qt = blockIdx.x;
    const int h  = blockIdx.y;
    const int b  = blockIdx.z;
    const int tid = threadIdx.x;
    const int lane = tid & 63, w = tid >> 6;
    const int lr = lane & 15, lk = lane >> 4;
    const int q0 = qt * 64;
    const float SCALEf = 0.10206207261596577f;

    __shared__ unsigned short Qs[64 * 104];
    __shared__ unsigned short Ks[64 * 104];
    __shared__ unsigned short Vt[32 * 68];
    __shared__ unsigned short Ps[4][16 * 68];

    // stage Q tile [64 q][96 d]
    const float* qbase = q + ((long)(b * Tt + q0)) * 1536 + h * 96;
    for (int u = tid; u < 64 * 24; u += 256) {
        int row = u / 24, c4 = u % 24;
        float4_t v = *(const float4_t*)(qbase + (long)row * 1536 + c4 * 4);
        uint2_t p; p.x = pack2bf(v.x, v.y); p.y = pack2bf(v.z, v.w);
        *(uint2_t*)&Qs[row * 104 + c4 * 4] = p;
    }
    __syncthreads();

    bf16x8 qf[3];
#pragma unroll
    for (int d = 0; d < 3; d++)
        qf[d] = *(bf16x8*)&Qs[(w * 16 + lr) * 104 + d * 32 + lk * 8];

    float mrow[4], ssum[4];
    f32x4 oacc[2];
#pragma unroll
    for (int r = 0; r < 4; r++) { mrow[r] = -1e30f; ssum[r] = 0.f; }
    oacc[0] = (f32x4){0.f,0.f,0.f,0.f};
    oacc[1] = (f32x4){0.f,0.f,0.f,0.f};

    int kb0 = 0, kb1 = SK;
    if (windowed) { kb0 = q0 - 256; if (kb0 < 0) kb0 = 0; kb1 = q0 + 64; }

    for (int kb = kb0; kb < kb1; kb += 64) {
        __syncthreads();   // previous PV reads done before restaging
        const float* kbase = Kb + ((long)(b * SK + kb)) * 1536 + h * 96;
        for (int u = tid; u < 64 * 24; u += 256) {
            int row = u / 24, c4 = u % 24;
            float4_t v = *(const float4_t*)(kbase + (long)row * 1536 + c4 * 4);
            uint2_t p; p.x = pack2bf(v.x, v.y); p.y = pack2bf(v.z, v.w);
            *(uint2_t*)&Ks[row * 104 + c4 * 4] = p;
        }
        const float* vbase = Vb + ((long)(b * SK + kb)) * 512 + h * 32;
        for (int u = tid; u < 2048; u += 256) {
            int key = u >> 5, d = u & 31;
            Vt[d * 68 + key] = bf16of(vbase[(long)key * 512 + d]);
        }
        __syncthreads();

        // QK^T: S[16q][64k] per wave
        f32x4 s[4];
#pragma unroll
        for (int ct = 0; ct < 4; ct++) {
            s[ct] = (f32x4){0.f,0.f,0.f,0.f};
#pragma unroll
            for (int kk = 0; kk < 3; kk++) {
                bf16x8 kf = *(bf16x8*)&Ks[(ct * 16 + lr) * 104 + kk * 32 + lk * 8];
                s[ct] = __builtin_amdgcn_mfma_f32_16x16x32_bf16(qf[kk], kf, s[ct], 0, 0, 0);
            }
        }

        // scale + mask
        float cm[4] = {-1e30f, -1e30f, -1e30f, -1e30f};
#pragma unroll
        for (int ct = 0; ct < 4; ct++) {
            int key = kb + ct * 16 + lr;
#pragma unroll
            for (int r = 0; r < 4; r++) {
                float sv = s[ct][r] * SCALEf;
                if (windowed) {
                    int t = q0 + w * 16 + lk * 4 + r;
                    if (!(key <= t && t - key < WINd)) sv = -1e30f;
                }
                s[ct][r] = sv;
                cm[r] = fmaxf(cm[r], sv);
            }
        }
        // row max across 16 lr lanes
#pragma unroll
        for (int off = 8; off > 0; off >>= 1) {
#pragma unroll
            for (int r = 0; r < 4; r++) cm[r] = fmaxf(cm[r], __shfl_xor(cm[r], off));
        }
        float alpha[4], rs[4];
#pragma unroll
        for (int r = 0; r < 4; r++) {
            float mn = fmaxf(mrow[r], cm[r]);
            alpha[r] = __expf(mrow[r] - mn);
            mrow[r] = mn;
            rs[r] = 0.f;
        }
        // p = exp(s-m), chunk row sums
#pragma unroll
        for (int ct = 0; ct < 4; ct++) {
#pragma unroll
            for (int r = 0; r < 4; r++) {
                float p = (s[ct][r] > -1e29f) ? __expf(s[ct][r] - mrow[r]) : 0.f;
                s[ct][r] = p;
                rs[r] += p;
            }
        }
#pragma unroll
        for (int off = 8; off > 0; off >>= 1) {
#pragma unroll
            for (int r = 0; r < 4; r++) rs[r] += __shfl_xor(rs[r], off);
        }
#pragma unroll
        for (int r = 0; r < 4; r++) ssum[r] = ssum[r] * alpha[r] + rs[r];
#pragma unroll
        for (int dt = 0; dt < 2; dt++)
#pragma unroll
            for (int r = 0; r < 4; r++) oacc[dt][r] *= alpha[r];

        // write P to per-wave LDS
#pragma unroll
        for (int ct = 0; ct < 4; ct++)
#pragma unroll
            for (int r = 0; r < 4; r++)
                Ps[w][(lk * 4 + r) * 68 + ct * 16 + lr] = bf16of(s[ct][r]);
        __syncthreads();

        // PV
        bf16x8 pf[2];
#pragma unroll
        for (int kk = 0; kk < 2; kk++)
            pf[kk] = *(bf16x8*)&Ps[w][lr * 68 + kk * 32 + lk * 8];
#pragma unroll
        for (int dt = 0; dt < 2; dt++) {
#pragma unroll
            for (int kk = 0; kk < 2; kk++) {
                bf16x8 vf = *(bf16x8*)&Vt[(dt * 16 + lr) * 68 + kk * 32 + lk * 8];
                oacc[dt] = __builtin_amdgcn_mfma_f32_16x16x32_bf16(pf[kk], vf, oacc[dt], 0, 0, 0);
            }
        }
    }

    // write out
#pragma unroll
    for (int dt = 0; dt < 2; dt++) {
#pragma unroll
        for (int r = 0; r < 4; r++) {
            int t = q0 + w * 16 + lk * 4 + r;
            o[((long)(b * Tt + t)) * 512 + h * 32 + dt * 16 + lr] = oacc[dt][r] / ssum[r];
        }
    }
}

// gate softmax + weighted combine
__global__ __launch_bounds__(256) void gatecomb_kernel(const float* __restrict__ x,
    const float* __restrict__ Wgate, const float* __restrict__ o1,
    const float* __restrict__ o2, const float* __restrict__ o3, float* __restrict__ comb)
{
    int tok = blockIdx.x, tid = threadIdx.x;
    __shared__ float r0[256], r1[256], r2[256];
    float l0 = 0.f, l1 = 0.f, l2 = 0.f;
    for (int c = tid; c < 1024; c += 256) {
        float xv = x[((long)tok << 10) + c];
        l0 += xv * Wgate[c * 3 + 0];
        l1 += xv * Wgate[c * 3 + 1];
        l2 += xv * Wgate[c * 3 + 2];
    }
    r0[tid] = l0; r1[tid] = l1; r2[tid] = l2; __syncthreads();
    for (int off = 128; off > 0; off >>= 1) {
        if (tid < off) { r0[tid] += r0[tid + off]; r1[tid] += r1[tid + off]; r2[tid] += r2[tid + off]; }
        __syncthreads();
    }
    float a = r0[0], bb = r1[0], cc = r2[0];
    float m = fmaxf(a, fmaxf(bb, cc));
    float e0 = expf(a - m), e1 = expf(bb - m), e2 = expf(cc - m);
    float sinv = 1.f / (e0 + e1 + e2);
    float g0 = e0 * sinv, g1 = e1 * sinv, g2 = e2 * sinv;
    for (int i = tid; i < 512; i += 256) {
        long idx = (long)tok * 512 + i;
        comb[idx] = g0 * o1[idx] + g1 * o2[idx] + g2 * o3[idx];
    }
}

extern "C" void kernel_launch(void* const* d_in, const int* in_sizes, int n_in,
                              void* d_out, int out_size, void* d_ws, size_t ws_size,
                              hipStream_t stream)
{
    const float* x     = (const float*)d_in[0];
    const float* Wcq   = (const float*)d_in[1];
    const float* qnw   = (const float*)d_in[2];
    const float* Wdqn  = (const float*)d_in[3];
    const float* Wdqr  = (const float*)d_in[4];
    const float* Wckv  = (const float*)d_in[5];
    const float* kvnw  = (const float*)d_in[6];
    const float* Wdkn  = (const float*)d_in[7];
    const float* Wdv   = (const float*)d_in[8];
    const float* Wkr   = (const float*)d_in[9];
    const float* Wimp  = (const float*)d_in[10];
    const float* Wselk = (const float*)d_in[11];
    const float* Wselv = (const float*)d_in[12];
    const float* Wwink = (const float*)d_in[13];
    const float* Wwinv = (const float*)d_in[14];
    const float* Wc1   = (const float*)d_in[15];
    const float* Wc2   = (const float*)d_in[16];
    const float* pos   = (const float*)d_in[17];
    const float* Wgate = (const float*)d_in[18];
    const float* Wproj = (const float*)d_in[19];
    float* out = (float*)d_out;

    float* ws = (float*)d_ws;
    size_t off = 0;
    auto alloc = [&](size_t n) { float* p = ws + off; off += n; return p; };
    float* q       = alloc(2048L * 1536);
    float* blocksA = alloc(128L * 16384);   // reused as qr after Wc1 GEMM
    float* hb      = alloc(128L * 4096);
    float* cb      = alloc(128L * 1024);
    float* nqraw   = alloc(2048L * 96);
    float* nq      = alloc(2048L * 96);
    float* qn      = alloc(2048L * 512);
    float* nkv     = alloc(128L * 32);
    float* kn      = alloc(128L * 512);
    float* v1      = alloc(128L * 512);
    float* krope   = alloc(128L * 64);
    float* k1      = alloc(128L * 1536);
    float* imp     = alloc(2048);
    float* winK    = alloc(2048L * 1536);
    float* winV    = alloc(2048L * 512);
    float* selK    = alloc(512L * 1536);
    float* selV    = alloc(512L * 512);
    float* o1      = alloc(2048L * 512);
    float* o2      = alloc(2048L * 512);
    float* o3      = alloc(2048L * 512);
    float* comb    = alloc(2048L * 512);
    int* rows      = (int*)alloc(512);
    float* qr      = blocksA;

    // ---- branch 1: block compression ----
    addpos_kernel<<<8192, 256, 0, stream>>>(x, pos, blocksA);
    hipMemsetAsync(hb, 0, 128L * 4096 * sizeof(float), stream);
    gemm_mfma<<<dim3(32, 1, 8), 256, 0, stream>>>(blocksA, Wc1, hb, 128, 4096, 16384, nullptr, 2);
    gelu_kernel<<<2048, 256, 0, stream>>>(hb);
    hipMemsetAsync(cb, 0, 128L * 1024 * sizeof(float), stream);
    gemm_mfma<<<dim3(8, 1, 8), 256, 0, stream>>>(hb, Wc2, cb, 128, 1024, 4096, nullptr, 2);

    // ---- queries ----
    hipMemsetAsync(nqraw, 0, 2048L * 96 * sizeof(float), stream);
    gemm_mfma<<<dim3(1, 16, 4), 256, 0, stream>>>(x, Wcq, nqraw, 2048, 96, 1024, nullptr, 2);
    rms96_kernel<<<2048, 128, 0, stream>>>(nqraw, qnw, nq);
    gemm_mfma<<<dim3(4, 16, 1), 256, 0, stream>>>(nq, Wdqn, qn, 2048, 512, 96, nullptr, 0);
    gemm_mfma<<<dim3(8, 16, 1), 256, 0, stream>>>(nq, Wdqr, qr, 2048, 1024, 96, nullptr, 0);
    rope_q_kernel<<<2048, 256, 0, stream>>>(qn, qr, q);

    // ---- branch 1 K/V ----
    nkv_kernel<<<128, 256, 0, stream>>>(cb, Wckv, kvnw, nkv);
    gemm_mfma<<<dim3(4, 1, 1), 256, 0, stream>>>(nkv, Wdkn, kn, 128, 512, 32, nullptr, 0);
    gemm_mfma<<<dim3(4, 1, 1), 256, 0, stream>>>(nkv, Wdv, v1, 128, 512, 32, nullptr, 0);
    krope_kernel<<<128, 256, 0, stream>>>(cb, Wkr, krope);
    k1_kernel<<<128, 256, 0, stream>>>(kn, krope, k1);

    // ---- branch 2: top-k selection ----
    imp_kernel<<<512, 256, 0, stream>>>(x, Wimp, imp);
    topk_kernel<<<2, 256, 0, stream>>>(imp, rows);
    hipMemsetAsync(selK, 0, 512L * 1536 * sizeof(float), stream);
    hipMemsetAsync(selV, 0, 512L * 512 * sizeof(float), stream);
    gemm_mfma<<<dim3(12, 4, 4), 256, 0, stream>>>(x, Wselk, selK, 512, 1536, 1024, rows, 2);
    gemm_mfma<<<dim3(4, 4, 8), 256, 0, stream>>>(x, Wselv, selV, 512, 512, 1024, rows, 2);

    // ---- branch 3: sliding window K/V ----
    gemm_mfma<<<dim3(12, 16, 1), 256, 0, stream>>>(x, Wwink, winK, 2048, 1536, 1024, nullptr, 0);
    hipMemsetAsync(winV, 0, 2048L * 512 * sizeof(float), stream);
    gemm_mfma<<<dim3(4, 16, 2), 256, 0, stream>>>(x, Wwinv, winV, 2048, 512, 1024, nullptr, 2);

    // ---- attention (three branches, MFMA flash) ----
    attn_mfma<<<dim3(16, Hh, Bsz), 256, 0, stream>>>(q, k1, v1, o1, 64, 0);
    attn_mfma<<<dim3(16, Hh, Bsz), 256, 0, stream>>>(q, selK, selV, o2, 256, 0);
    attn_mfma<<<dim3(16, Hh, Bsz), 256, 0, stream>>>(q, winK, winV, o3, Tt, 1);

    // ---- gate + combine + output projection ----
    gatecomb_kernel<<<2048, 256, 0, stream>>>(x, Wgate, o1, o2, o3, comb);
    gemm_mfma<<<dim3(8, 16, 1), 256, 0, stream>>>(comb, Wproj, out, 2048, 1024, 512, nullptr, 0);
}

// Round 7
// 1373.013 us; speedup vs baseline: 2.8081x; 1.2257x over previous
//
#include <hip/hip_runtime.h>
#include <hip/hip_bf16.h>
#include <cmath>

#define Bsz 2
#define Tt 1024
#define Cc 1024
#define Hh 16
#define WINd 256
#define KEEPd 256
#define EPSF 1e-6f

typedef __attribute__((ext_vector_type(8))) short bf16x8;
typedef __attribute__((ext_vector_type(4))) float f32x4;
typedef __attribute__((ext_vector_type(4))) float float4_t;
typedef __attribute__((ext_vector_type(2))) unsigned int uint2_t;

static __device__ __forceinline__ float gelu_exact(float v) {
    return 0.5f * v * (1.f + erff(v * 0.70710678118654752f));
}

static __device__ __forceinline__ unsigned int pack2bf(float lo, float hi) {
    unsigned a = __float_as_uint(lo);
    unsigned b = __float_as_uint(hi);
    a = (a + 0x7FFFu + ((a >> 16) & 1u)) >> 16;
    b = (b + 0x7FFFu + ((b >> 16) & 1u)) >> 16;
    return (b << 16) | (a & 0xFFFFu);
}

static __device__ __forceinline__ unsigned short bf16of(float v) {
    unsigned a = __float_as_uint(v);
    a = (a + 0x7FFFu + ((a >> 16) & 1u)) >> 16;
    return (unsigned short)a;
}

// bf16-MFMA GEMM: C[M,N] = A[M,K] @ B[K,N], fp32 in/out.
// flags: bit1(2)=atomicAdd epilogue (split-K); bit2(4)=A is x with intra-block
// pos-enc fused (Wc1 path: arow=(b,nb), col=blk*1024+c, A <- x[b,nb*16+blk,c]+pos[col]);
// bit3(8)=gelu applied to A during staging.
__global__ __launch_bounds__(256) void gemm_mfma(
    const float* __restrict__ A, const float* __restrict__ B, float* __restrict__ C,
    int M, int N, int K, const int* __restrict__ a_rows, int flags,
    const float* __restrict__ posp)
{
    __shared__ unsigned short As[128 * 40];
    __shared__ unsigned short Bs[128 * 40];
    const int tid = threadIdx.x;
    const int bn = blockIdx.x * 128;
    const int bm = blockIdx.y * 128;
    const int kslice = K / gridDim.z;
    const int k_begin = blockIdx.z * kslice;
    const int k_end = k_begin + kslice;

    const int lane = tid & 63;
    const int w = tid >> 6;
    const int wr = w >> 1, wc = w & 1;
    const int lr = lane & 15, lk = lane >> 4;

    f32x4 acc[4][4];
#pragma unroll
    for (int i = 0; i < 4; i++)
#pragma unroll
        for (int j = 0; j < 4; j++) acc[i][j] = (f32x4){0.f, 0.f, 0.f, 0.f};

    for (int k0 = k_begin; k0 < k_end; k0 += 32) {
#pragma unroll
        for (int l = 0; l < 4; l++) {
            int u = tid + l * 256;
            int row = u >> 3, qq = u & 7;
            int arow = a_rows ? a_rows[bm + row] : bm + row;
            float4_t va;
            if (flags & 4) {
                // fused addpos: A==x, arow in [0,128): b=arow>>6, nb=arow&63
                int col = k0 + qq * 4;
                int blk = col >> 10, c = col & 1023;
                long t = ((long)(arow >> 6) << 10) + ((arow & 63) << 4) + blk;
                va = *(const float4_t*)(A + (t << 10) + c);
                float4_t pv = *(const float4_t*)(posp + col);
                va.x += pv.x; va.y += pv.y; va.z += pv.z; va.w += pv.w;
            } else {
                va = *(const float4_t*)(A + (long)arow * K + k0 + qq * 4);
            }
            if (flags & 8) {
                va.x = gelu_exact(va.x); va.y = gelu_exact(va.y);
                va.z = gelu_exact(va.z); va.w = gelu_exact(va.w);
            }
            uint2_t p;
            p.x = pack2bf(va.x, va.y);
            p.y = pack2bf(va.z, va.w);
            *(uint2_t*)&As[row * 40 + qq * 4] = p;
        }
#pragma unroll
        for (int l = 0; l < 8; l++) {
            int u = tid + l * 256;
            int kp = u >> 7, n = u & 127;
            int col = bn + n;
            float lo = 0.f, hi = 0.f;
            if (col < N) {
                lo = B[(long)(k0 + 2 * kp) * N + col];
                hi = B[(long)(k0 + 2 * kp + 1) * N + col];
            }
            *(unsigned int*)&Bs[n * 40 + kp * 2] = pack2bf(lo, hi);
        }
        __syncthreads();
        bf16x8 af[4], bfr[4];
#pragma unroll
        for (int i = 0; i < 4; i++)
            af[i] = *(bf16x8*)&As[(wr * 64 + i * 16 + lr) * 40 + lk * 8];
#pragma unroll
        for (int j = 0; j < 4; j++)
            bfr[j] = *(bf16x8*)&Bs[(wc * 64 + j * 16 + lr) * 40 + lk * 8];
#pragma unroll
        for (int i = 0; i < 4; i++)
#pragma unroll
            for (int j = 0; j < 4; j++)
                acc[i][j] = __builtin_amdgcn_mfma_f32_16x16x32_bf16(af[i], bfr[j], acc[i][j], 0, 0, 0);
        __syncthreads();
    }

#pragma unroll
    for (int i = 0; i < 4; i++) {
#pragma unroll
        for (int j = 0; j < 4; j++) {
            int col = bn + wc * 64 + j * 16 + lr;
            if (col < N) {
#pragma unroll
                for (int r = 0; r < 4; r++) {
                    int row = bm + wr * 64 + i * 16 + lk * 4 + r;
                    long idx = (long)row * N + col;
                    if (flags & 2) atomicAdd(&C[idx], acc[i][j][r]);
                    else C[idx] = acc[i][j][r];
                }
            }
        }
    }
}

// RMSNorm over 96-dim rows
__global__ __launch_bounds__(128) void rms96_kernel(const float* __restrict__ raw,
    const float* __restrict__ wgt, float* __restrict__ out)
{
    int tok = blockIdx.x, tid = threadIdx.x;
    __shared__ float sq[128];
    __shared__ float msh;
    float v = 0.f;
    if (tid < 96) v = raw[tok * 96 + tid];
    sq[tid] = v * v;
    __syncthreads();
    if (tid < 32) {
        float s = sq[tid] + sq[tid + 32] + sq[tid + 64];
        for (int off = 16; off > 0; off >>= 1) s += __shfl_down(s, off);
        if (tid == 0) msh = s * (1.f / 96.f);
    }
    __syncthreads();
    if (tid < 96) out[tok * 96 + tid] = v * rsqrtf(msh + EPSF) * wgt[tid];
}

// q[tok][h*96+d]: d<32 -> qn head slice; d>=32 -> rope(qr) at position t
__global__ __launch_bounds__(256) void rope_q_kernel(const float* __restrict__ qn,
    const float* __restrict__ qr, float* __restrict__ q)
{
    int tok = blockIdx.x, tid = threadIdx.x;
    int t = tok & (Tt - 1);
#pragma unroll
    for (int l = 0; l < 6; l++) {
        int e = tid + l * 256;
        int h = e / 96, d = e % 96;
        float val;
        if (d < 32) val = qn[(long)tok * 512 + h * 32 + d];
        else {
            int dd = d - 32;
            int i = (dd < 32) ? dd : dd - 32;
            float freq = powf(10000.f, -(float)i * (1.f / 32.f));
            float ang = (float)t * freq;
            float sn = sinf(ang), cs = cosf(ang);
            if (dd < 32) val = qr[(long)tok * 1024 + h * 64 + dd] * cs - qr[(long)tok * 1024 + h * 64 + dd + 32] * sn;
            else         val = qr[(long)tok * 1024 + h * 64 + i] * sn + qr[(long)tok * 1024 + h * 64 + dd] * cs;
        }
        q[(long)tok * 1536 + e] = val;
    }
}

// nkv = RMSNorm(cb @ Wckv) * kvnw   [128, 32]
__global__ __launch_bounds__(256) void nkv_kernel(const float* __restrict__ cb,
    const float* __restrict__ Wckv, const float* __restrict__ kvnw, float* __restrict__ nkv)
{
    int row = blockIdx.x, tid = threadIdx.x;
    __shared__ float cs[1024];
    __shared__ float red[256];
    __shared__ float vals[32];
    for (int c = tid; c < 1024; c += 256) cs[c] = cb[((long)row << 10) + c];
    __syncthreads();
    int j = tid & 31, g = tid >> 5;
    float acc = 0.f;
    for (int c = g * 128; c < g * 128 + 128; c++) acc += cs[c] * Wckv[c * 32 + j];
    red[tid] = acc; __syncthreads();
    if (tid < 128) red[tid] += red[tid + 128]; __syncthreads();
    if (tid < 64) red[tid] += red[tid + 64]; __syncthreads();
    if (tid < 32) { float v = red[tid] + red[tid + 32]; vals[tid] = v; red[tid] = v * v; }
    __syncthreads();
    if (tid < 16) red[tid] += red[tid + 16]; __syncthreads();
    if (tid < 8) red[tid] += red[tid + 8]; __syncthreads();
    if (tid < 4) red[tid] += red[tid + 4]; __syncthreads();
    if (tid < 2) red[tid] += red[tid + 2]; __syncthreads();
    if (tid < 1) red[0] += red[1]; __syncthreads();
    float mean = red[0] * (1.f / 32.f);
    if (tid < 32) nkv[row * 32 + tid] = vals[tid] * rsqrtf(mean + EPSF) * kvnw[tid];
}

// krope = rope((cb @ Wkr)/16) at position nb   [128, 64]
__global__ __launch_bounds__(256) void krope_kernel(const float* __restrict__ cb,
    const float* __restrict__ Wkr, float* __restrict__ krope)
{
    int row = blockIdx.x, tid = threadIdx.x;
    int nb = row & 63;
    __shared__ float cs[1024];
    __shared__ float red[256];
    __shared__ float raw[64];
    for (int c = tid; c < 1024; c += 256) cs[c] = cb[((long)row << 10) + c];
    __syncthreads();
    int d = tid & 63, g = tid >> 6;
    float acc = 0.f;
    for (int c = g * 256; c < g * 256 + 256; c++) acc += cs[c] * Wkr[c * 64 + d];
    red[tid] = acc; __syncthreads();
    if (tid < 128) red[tid] += red[tid + 128]; __syncthreads();
    if (tid < 64) raw[tid] = red[tid] + red[tid + 64];
    __syncthreads();
    if (tid < 64) {
        int dd = tid;
        int i = (dd < 32) ? dd : dd - 32;
        float freq = powf(10000.f, -(float)i * (1.f / 32.f));
        float ang = (float)nb * freq;
        float sn = sinf(ang), c2 = cosf(ang);
        float val;
        if (dd < 32) val = raw[dd] * c2 - raw[dd + 32] * sn;
        else         val = raw[i] * sn + raw[dd] * c2;
        krope[row * 64 + dd] = val * (1.f / 16.f);
    }
}

// k1[row][h*96+d] = d<32 ? kn[row][h*32+d] : krope[row][d-32]
__global__ void k1_kernel(const float* __restrict__ kn, const float* __restrict__ krope,
                          float* __restrict__ k1) {
    int row = blockIdx.x, tid = threadIdx.x;
#pragma unroll
    for (int l = 0; l < 6; l++) {
        int e = tid + l * 256;
        int h = e / 96, d = e % 96;
        k1[(long)row * 1536 + e] = (d < 32) ? kn[row * 512 + h * 32 + d] : krope[row * 64 + d - 32];
    }
}

// imp[b*T+t] = x[b,t,:] . Wimp
__global__ void imp_kernel(const float* __restrict__ x, const float* __restrict__ Wimp,
                           float* __restrict__ imp) {
    int tid = threadIdx.x;
    int w = tid >> 6, lane = tid & 63;
    int tok = blockIdx.x * 4 + w;
    float acc = 0.f;
    for (int c = lane; c < 1024; c += 64) acc += x[((long)tok << 10) + c] * Wimp[c];
    for (int off = 32; off > 0; off >>= 1) acc += __shfl_down(acc, off);
    if (lane == 0) imp[tok] = acc;
}

// exact top-256 by rank, sorted compaction
__global__ __launch_bounds__(256) void topk_kernel(const float* __restrict__ imp,
                                                   int* __restrict__ rows) {
    int b = blockIdx.x, tid = threadIdx.x;
    __shared__ float v[1024];
    __shared__ int flag[1024];
    for (int i = tid; i < 1024; i += 256) v[i] = imp[b * 1024 + i];
    __syncthreads();
    for (int i = tid; i < 1024; i += 256) {
        float vi = v[i]; int r = 0;
        for (int j = 0; j < 1024; j++) {
            float vj = v[j];
            r += (vj > vi) || (vj == vi && j < i);
        }
        flag[i] = (r < KEEPd) ? 1 : 0;
    }
    __syncthreads();
    for (int i = tid; i < 1024; i += 256) {
        if (flag[i]) {
            int p = 0;
            for (int j = 0; j < i; j++) p += flag[j];
            rows[b * KEEPd + p] = b * 1024 + i;
        }
    }
}

// MFMA flash attention: one block = (b, h, 64-query tile); 4 waves x 16 queries.
__global__ __launch_bounds__(256) void attn_mfma(
    const float* __restrict__ q, const float* __restrict__ Kb, const float* __restrict__ Vb,
    float* __restrict__ o, int SK, int windowed)
{
    const int qt = blockIdx.x;
    const int h  = blockIdx.y;
    const int b  = blockIdx.z;
    const int tid = threadIdx.x;
    const int lane = tid & 63, w = tid >> 6;
    const int lr = lane & 15, lk = lane >> 4;
    const int q0 = qt * 64;
    const float SCALEf = 0.10206207261596577f;

    __shared__ unsigned short Qs[64 * 104];
    __shared__ unsigned short Ks[64 * 104];
    __shared__ unsigned short Vt[32 * 68];
    __shared__ unsigned short Ps[4][16 * 68];

    const float* qbase = q + ((long)(b * Tt + q0)) * 1536 + h * 96;
    for (int u = tid; u < 64 * 24; u += 256) {
        int row = u / 24, c4 = u % 24;
        float4_t v = *(const float4_t*)(qbase + (long)row * 1536 + c4 * 4);
        uint2_t p; p.x = pack2bf(v.x, v.y); p.y = pack2bf(v.z, v.w);
        *(uint2_t*)&Qs[row * 104 + c4 * 4] = p;
    }
    __syncthreads();

    bf16x8 qf[3];
#pragma unroll
    for (int d = 0; d < 3; d++)
        qf[d] = *(bf16x8*)&Qs[(w * 16 + lr) * 104 + d * 32 + lk * 8];

    float mrow[4], ssum[4];
    f32x4 oacc[2];
#pragma unroll
    for (int r = 0; r < 4; r++) { mrow[r] = -1e30f; ssum[r] = 0.f; }
    oacc[0] = (f32x4){0.f,0.f,0.f,0.f};
    oacc[1] = (f32x4){0.f,0.f,0.f,0.f};

    int kb0 = 0, kb1 = SK;
    if (windowed) { kb0 = q0 - 256; if (kb0 < 0) kb0 = 0; kb1 = q0 + 64; }

    for (int kb = kb0; kb < kb1; kb += 64) {
        __syncthreads();
        const float* kbase = Kb + ((long)(b * SK + kb)) * 1536 + h * 96;
        for (int u = tid; u < 64 * 24; u += 256) {
            int row = u / 24, c4 = u % 24;
            float4_t v = *(const float4_t*)(kbase + (long)row * 1536 + c4 * 4);
            uint2_t p; p.x = pack2bf(v.x, v.y); p.y = pack2bf(v.z, v.w);
            *(uint2_t*)&Ks[row * 104 + c4 * 4] = p;
        }
        const float* vbase = Vb + ((long)(b * SK + kb)) * 512 + h * 32;
        for (int u = tid; u < 2048; u += 256) {
            int key = u >> 5, d = u & 31;
            Vt[d * 68 + key] = bf16of(vbase[(long)key * 512 + d]);
        }
        __syncthreads();

        f32x4 s[4];
#pragma unroll
        for (int ct = 0; ct < 4; ct++) {
            s[ct] = (f32x4){0.f,0.f,0.f,0.f};
#pragma unroll
            for (int kk = 0; kk < 3; kk++) {
                bf16x8 kf = *(bf16x8*)&Ks[(ct * 16 + lr) * 104 + kk * 32 + lk * 8];
                s[ct] = __builtin_amdgcn_mfma_f32_16x16x32_bf16(qf[kk], kf, s[ct], 0, 0, 0);
            }
        }

        float cm[4] = {-1e30f, -1e30f, -1e30f, -1e30f};
#pragma unroll
        for (int ct = 0; ct < 4; ct++) {
            int key = kb + ct * 16 + lr;
#pragma unroll
            for (int r = 0; r < 4; r++) {
                float sv = s[ct][r] * SCALEf;
                if (windowed) {
                    int t = q0 + w * 16 + lk * 4 + r;
                    if (!(key <= t && t - key < WINd)) sv = -1e30f;
                }
                s[ct][r] = sv;
                cm[r] = fmaxf(cm[r], sv);
            }
        }
#pragma unroll
        for (int off = 8; off > 0; off >>= 1) {
#pragma unroll
            for (int r = 0; r < 4; r++) cm[r] = fmaxf(cm[r], __shfl_xor(cm[r], off));
        }
        float alpha[4], rs[4];
#pragma unroll
        for (int r = 0; r < 4; r++) {
            float mn = fmaxf(mrow[r], cm[r]);
            alpha[r] = __expf(mrow[r] - mn);
            mrow[r] = mn;
            rs[r] = 0.f;
        }
#pragma unroll
        for (int ct = 0; ct < 4; ct++) {
#pragma unroll
            for (int r = 0; r < 4; r++) {
                float p = (s[ct][r] > -1e29f) ? __expf(s[ct][r] - mrow[r]) : 0.f;
                s[ct][r] = p;
                rs[r] += p;
            }
        }
#pragma unroll
        for (int off = 8; off > 0; off >>= 1) {
#pragma unroll
            for (int r = 0; r < 4; r++) rs[r] += __shfl_xor(rs[r], off);
        }
#pragma unroll
        for (int r = 0; r < 4; r++) ssum[r] = ssum[r] * alpha[r] + rs[r];
#pragma unroll
        for (int dt = 0; dt < 2; dt++)
#pragma unroll
            for (int r = 0; r < 4; r++) oacc[dt][r] *= alpha[r];

#pragma unroll
        for (int ct = 0; ct < 4; ct++)
#pragma unroll
            for (int r = 0; r < 4; r++)
                Ps[w][(lk * 4 + r) * 68 + ct * 16 + lr] = bf16of(s[ct][r]);
        __syncthreads();

        bf16x8 pf[2];
#pragma unroll
        for (int kk = 0; kk < 2; kk++)
            pf[kk] = *(bf16x8*)&Ps[w][lr * 68 + kk * 32 + lk * 8];
#pragma unroll
        for (int dt = 0; dt < 2; dt++) {
#pragma unroll
            for (int kk = 0; kk < 2; kk++) {
                bf16x8 vf = *(bf16x8*)&Vt[(dt * 16 + lr) * 68 + kk * 32 + lk * 8];
                oacc[dt] = __builtin_amdgcn_mfma_f32_16x16x32_bf16(pf[kk], vf, oacc[dt], 0, 0, 0);
            }
        }
    }

#pragma unroll
    for (int dt = 0; dt < 2; dt++) {
#pragma unroll
        for (int r = 0; r < 4; r++) {
            int t = q0 + w * 16 + lk * 4 + r;
            o[((long)(b * Tt + t)) * 512 + h * 32 + dt * 16 + lr] = oacc[dt][r] / ssum[r];
        }
    }
}

// gate softmax + weighted combine
__global__ __launch_bounds__(256) void gatecomb_kernel(const float* __restrict__ x,
    const float* __restrict__ Wgate, const float* __restrict__ o1,
    const float* __restrict__ o2, const float* __restrict__ o3, float* __restrict__ comb)
{
    int tok = blockIdx.x, tid = threadIdx.x;
    __shared__ float r0[256], r1[256], r2[256];
    float l0 = 0.f, l1 = 0.f, l2 = 0.f;
    for (int c = tid; c < 1024; c += 256) {
        float xv = x[((long)tok << 10) + c];
        l0 += xv * Wgate[c * 3 + 0];
        l1 += xv * Wgate[c * 3 + 1];
        l2 += xv * Wgate[c * 3 + 2];
    }
    r0[tid] = l0; r1[tid] = l1; r2[tid] = l2; __syncthreads();
    for (int off = 128; off > 0; off >>= 1) {
        if (tid < off) { r0[tid] += r0[tid + off]; r1[tid] += r1[tid + off]; r2[tid] += r2[tid + off]; }
        __syncthreads();
    }
    float a = r0[0], bb = r1[0], cc = r2[0];
    float m = fmaxf(a, fmaxf(bb, cc));
    float e0 = expf(a - m), e1 = expf(bb - m), e2 = expf(cc - m);
    float sinv = 1.f / (e0 + e1 + e2);
    float g0 = e0 * sinv, g1 = e1 * sinv, g2 = e2 * sinv;
    for (int i = tid; i < 512; i += 256) {
        long idx = (long)tok * 512 + i;
        comb[idx] = g0 * o1[idx] + g1 * o2[idx] + g2 * o3[idx];
    }
}

extern "C" void kernel_launch(void* const* d_in, const int* in_sizes, int n_in,
                              void* d_out, int out_size, void* d_ws, size_t ws_size,
                              hipStream_t stream)
{
    const float* x     = (const float*)d_in[0];
    const float* Wcq   = (const float*)d_in[1];
    const float* qnw   = (const float*)d_in[2];
    const float* Wdqn  = (const float*)d_in[3];
    const float* Wdqr  = (const float*)d_in[4];
    const float* Wckv  = (const float*)d_in[5];
    const float* kvnw  = (const float*)d_in[6];
    const float* Wdkn  = (const float*)d_in[7];
    const float* Wdv   = (const float*)d_in[8];
    const float* Wkr   = (const float*)d_in[9];
    const float* Wimp  = (const float*)d_in[10];
    const float* Wselk = (const float*)d_in[11];
    const float* Wselv = (const float*)d_in[12];
    const float* Wwink = (const float*)d_in[13];
    const float* Wwinv = (const float*)d_in[14];
    const float* Wc1   = (const float*)d_in[15];
    const float* Wc2   = (const float*)d_in[16];
    const float* pos   = (const float*)d_in[17];
    const float* Wgate = (const float*)d_in[18];
    const float* Wproj = (const float*)d_in[19];
    float* out = (float*)d_out;

    float* ws = (float*)d_ws;
    size_t off = 0;
    auto alloc = [&](size_t n) { float* p = ws + off; off += n; return p; };
    float* q       = alloc(2048L * 1536);
    float* qr      = alloc(2048L * 1024);
    float* hb      = alloc(128L * 4096);
    float* cb      = alloc(128L * 1024);
    float* nqraw   = alloc(2048L * 96);
    float* nq      = alloc(2048L * 96);
    float* qn      = alloc(2048L * 512);
    float* nkv     = alloc(128L * 32);
    float* kn      = alloc(128L * 512);
    float* v1      = alloc(128L * 512);
    float* krope   = alloc(128L * 64);
    float* k1      = alloc(128L * 1536);
    float* imp     = alloc(2048);
    float* winK    = alloc(2048L * 1536);
    float* winV    = alloc(2048L * 512);
    float* selK    = alloc(512L * 1536);
    float* selV    = alloc(512L * 512);
    float* o1      = alloc(2048L * 512);
    float* o2      = alloc(2048L * 512);
    float* o3      = alloc(2048L * 512);
    float* comb    = alloc(2048L * 512);
    int* rows      = (int*)alloc(512);

    // ---- branch 1: block compression (addpos fused into Wc1 A-staging) ----
    hipMemsetAsync(hb, 0, 128L * 4096 * sizeof(float), stream);
    gemm_mfma<<<dim3(32, 1, 32), 256, 0, stream>>>(x, Wc1, hb, 128, 4096, 16384, nullptr, 2 | 4, pos);
    hipMemsetAsync(cb, 0, 128L * 1024 * sizeof(float), stream);
    gemm_mfma<<<dim3(8, 1, 32), 256, 0, stream>>>(hb, Wc2, cb, 128, 1024, 4096, nullptr, 2 | 8, nullptr);

    // ---- queries ----
    hipMemsetAsync(nqraw, 0, 2048L * 96 * sizeof(float), stream);
    gemm_mfma<<<dim3(1, 16, 16), 256, 0, stream>>>(x, Wcq, nqraw, 2048, 96, 1024, nullptr, 2, nullptr);
    rms96_kernel<<<2048, 128, 0, stream>>>(nqraw, qnw, nq);
    gemm_mfma<<<dim3(4, 16, 1), 256, 0, stream>>>(nq, Wdqn, qn, 2048, 512, 96, nullptr, 0, nullptr);
    gemm_mfma<<<dim3(8, 16, 1), 256, 0, stream>>>(nq, Wdqr, qr, 2048, 1024, 96, nullptr, 0, nullptr);
    rope_q_kernel<<<2048, 256, 0, stream>>>(qn, qr, q);

    // ---- branch 1 K/V ----
    nkv_kernel<<<128, 256, 0, stream>>>(cb, Wckv, kvnw, nkv);
    gemm_mfma<<<dim3(4, 1, 1), 256, 0, stream>>>(nkv, Wdkn, kn, 128, 512, 32, nullptr, 0, nullptr);
    gemm_mfma<<<dim3(4, 1, 1), 256, 0, stream>>>(nkv, Wdv, v1, 128, 512, 32, nullptr, 0, nullptr);
    krope_kernel<<<128, 256, 0, stream>>>(cb, Wkr, krope);
    k1_kernel<<<128, 256, 0, stream>>>(kn, krope, k1);

    // ---- branch 2: top-k selection ----
    imp_kernel<<<512, 256, 0, stream>>>(x, Wimp, imp);
    topk_kernel<<<2, 256, 0, stream>>>(imp, rows);
    hipMemsetAsync(selK, 0, 512L * 1536 * sizeof(float), stream);
    hipMemsetAsync(selV, 0, 512L * 512 * sizeof(float), stream);
    gemm_mfma<<<dim3(12, 4, 8), 256, 0, stream>>>(x, Wselk, selK, 512, 1536, 1024, rows, 2, nullptr);
    gemm_mfma<<<dim3(4, 4, 16), 256, 0, stream>>>(x, Wselv, selV, 512, 512, 1024, rows, 2, nullptr);

    // ---- branch 3: sliding window K/V ----
    hipMemsetAsync(winK, 0, 2048L * 1536 * sizeof(float), stream);
    gemm_mfma<<<dim3(12, 16, 2), 256, 0, stream>>>(x, Wwink, winK, 2048, 1536, 1024, nullptr, 2, nullptr);
    hipMemsetAsync(winV, 0, 2048L * 512 * sizeof(float), stream);
    gemm_mfma<<<dim3(4, 16, 4), 256, 0, stream>>>(x, Wwinv, winV, 2048, 512, 1024, nullptr, 2, nullptr);

    // ---- attention (three branches, MFMA flash) ----
    attn_mfma<<<dim3(16, Hh, Bsz), 256, 0, stream>>>(q, k1, v1, o1, 64, 0);
    attn_mfma<<<dim3(16, Hh, Bsz), 256, 0, stream>>>(q, selK, selV, o2, 256, 0);
    attn_mfma<<<dim3(16, Hh, Bsz), 256, 0, stream>>>(q, winK, winV, o3, Tt, 1);

    // ---- gate + combine + output projection ----
    gatecomb_kernel<<<2048, 256, 0, stream>>>(x, Wgate, o1, o2, o3, comb);
    hipMemsetAsync(out, 0, 2048L * 1024 * sizeof(float), stream);
    gemm_mfma<<<dim3(8, 16, 2), 256, 0, stream>>>(comb, Wproj, out, 2048, 1024, 512, nullptr, 2, nullptr);
}